// Round 7
// baseline (302.606 us; speedup 1.0000x reference)
//
#include <hip/hip_runtime.h>
#include <hip/hip_fp16.h>
#include <stdint.h>

#define B_    64
#define T_    512
#define OBS_  128
#define FEAT_ 512
#define H_    256
#define G_    768
#define BT_   32768
#define NSLOT 16

typedef _Float16 f16x8 __attribute__((ext_vector_type(8)));
typedef float    f32x4 __attribute__((ext_vector_type(4)));

__device__ __forceinline__ uint32_t h2u(__half2 h){ union{ __half2 h; uint32_t u; } c; c.h = h; return c.u; }
__device__ __forceinline__ __half2 u2h(uint32_t u){ union{ uint32_t u; __half2 h; } c; c.u = u; return c.h; }

// swizzled LDS byte offset for GEMM tiles: [128 rows][8 chunks of 16B], chunk ^= row&7
__device__ __forceinline__ int sw(int r, int c) { return r * 128 + ((c ^ (r & 7)) << 4); }

__device__ __forceinline__ uint4 cvt8(float4 a, float4 b) {
    uint4 u;
    u.x = h2u(__floats2half2_rn(a.x, a.y));
    u.y = h2u(__floats2half2_rn(a.z, a.w));
    u.z = h2u(__floats2half2_rn(b.x, b.y));
    u.w = h2u(__floats2half2_rn(b.z, b.w));
    return u;
}

// ---------------------------------------------------------------------------
// MFMA GEMM: C[M x N](fp16) = act( A[M x K] @ W[N x K]^T + bias )
// 128x128 tile, BK=64, 4 waves (2x2), each wave 4x4 frags of 16x16x32_f16.
// (unchanged -- passed r3/r4/r6)
// ---------------------------------------------------------------------------
template<int KD, bool AF32, bool RELU>
__global__ __launch_bounds__(256, 2)
void mfma_gemm(const float* __restrict__ Af, const __half* __restrict__ Ah,
               const __half* __restrict__ Bh, const float* __restrict__ bias,
               uint32_t* __restrict__ C, int N)
{
    __shared__ __align__(16) __half As[128 * 64];
    __shared__ __align__(16) __half Bs[128 * 64];
    const int m0 = blockIdx.x * 128, n0 = blockIdx.y * 128;
    const int tid = threadIdx.x;
    const int r = tid >> 1, cb = (tid & 1) * 4;
    const int lane = tid & 63, w = tid >> 6;
    const int wm = w >> 1, wn = w & 1;
    const int l15 = lane & 15, lq = lane >> 4;
    constexpr int KT = KD / 64;

    f32x4 acc[4][4];
    #pragma unroll
    for (int i = 0; i < 4; ++i)
        #pragma unroll
        for (int j = 0; j < 4; ++j) {
            f32x4 z = {0.f, 0.f, 0.f, 0.f};
            acc[i][j] = z;
        }

    uint4 sa[4], sb[4];
    float4 sa32[8];

    auto loads = [&](int kt) {
        if constexpr (AF32) {
            const float* ap = Af + (size_t)(m0 + r) * KD + kt * 64 + cb * 8;
            #pragma unroll
            for (int c = 0; c < 4; ++c) {
                sa32[2 * c]     = ((const float4*)ap)[2 * c];
                sa32[2 * c + 1] = ((const float4*)ap)[2 * c + 1];
            }
        } else {
            const __half* ap = Ah + (size_t)(m0 + r) * KD + kt * 64 + cb * 8;
            #pragma unroll
            for (int c = 0; c < 4; ++c) sa[c] = ((const uint4*)ap)[c];
        }
        const __half* bp = Bh + (size_t)(n0 + r) * KD + kt * 64 + cb * 8;
        #pragma unroll
        for (int c = 0; c < 4; ++c) sb[c] = ((const uint4*)bp)[c];
    };

    auto dswrite = [&]() {
        #pragma unroll
        for (int c = 0; c < 4; ++c) {
            uint4 va;
            if constexpr (AF32) va = cvt8(sa32[2 * c], sa32[2 * c + 1]);
            else                va = sa[c];
            *(uint4*)((char*)As + sw(r, cb + c)) = va;
            *(uint4*)((char*)Bs + sw(r, cb + c)) = sb[c];
        }
    };

    auto compute = [&]() {
        #pragma unroll
        for (int kc = 0; kc < 2; ++kc) {
            f16x8 af[4], bf[4];
            #pragma unroll
            for (int mi = 0; mi < 4; ++mi)
                af[mi] = *(const f16x8*)((const char*)As + sw(wm * 64 + mi * 16 + l15, kc * 4 + lq));
            #pragma unroll
            for (int ni = 0; ni < 4; ++ni)
                bf[ni] = *(const f16x8*)((const char*)Bs + sw(wn * 64 + ni * 16 + l15, kc * 4 + lq));
            #pragma unroll
            for (int mi = 0; mi < 4; ++mi)
                #pragma unroll
                for (int ni = 0; ni < 4; ++ni)
                    acc[mi][ni] = __builtin_amdgcn_mfma_f32_16x16x32_f16(af[mi], bf[ni], acc[mi][ni], 0, 0, 0);
        }
    };

    loads(0);
    for (int kt = 0; kt < KT; ++kt) {
        __syncthreads();
        dswrite();
        __syncthreads();
        if (kt + 1 < KT) loads(kt + 1);
        compute();
    }

    #pragma unroll
    for (int ni = 0; ni < 4; ++ni) {
        const int col = n0 + wn * 64 + ni * 16 + l15;
        const float bv = bias[col];
        #pragma unroll
        for (int mi = 0; mi < 4; ++mi) {
            f32x4 d = acc[mi][ni];
            #pragma unroll
            for (int rr = 0; rr < 4; ++rr) {
                float v = d[rr] + bv;
                if (RELU) v = fmaxf(v, 0.0f);
                uint32_t u = (uint32_t)__half_as_ushort(__float2half(v));
                uint32_t nb = (uint32_t)__shfl_xor((int)u, 1);
                if (!(lane & 1)) {
                    const int row = m0 + wm * 64 + mi * 16 + lq * 4 + rr;
                    C[(size_t)row * (N >> 1) + (col >> 1)] = u | (nb << 16);
                }
            }
        }
    }
}

// ---------------------------------------------------------------------------
// Weight packs (fp32 -> fp16). pack_whh zeroes qctl[0..2] and emits W_hh in
// MFMA A-fragment per-lane order (unchanged layout, passed r6).
// ---------------------------------------------------------------------------
__global__ void pack_half(const float* __restrict__ in, uint32_t* __restrict__ out, int n2)
{
    int i = blockIdx.x * 256 + threadIdx.x;
    if (i < n2) {
        float2 f = ((const float2*)in)[i];
        out[i] = h2u(__floats2half2_rn(f.x, f.y));
    }
}

__global__ void pack_whh(const float* __restrict__ Whh, uint32_t* __restrict__ out,
                         int* __restrict__ qctl)
{
    if (blockIdx.x == 0 && threadIdx.x == 0) { qctl[0] = 0; qctl[1] = 0; qctl[2] = 0; }
    int p = blockIdx.x * 256 + threadIdx.x;
    if (p >= 512 * 192) return;
    const int v4 = p >> 2, sub = p & 3;
    const int t = v4 / 48, ic = v4 - t * 48;
    const int i = ic >> 3, c = ic & 7;
    const int w = t >> 6, lane = t & 63;
    const int row = w * 96 + i * 16 + (lane & 15);
    const int kb = c * 32 + ((lane >> 4) << 3) + sub * 2;
    out[p] = h2u(__floats2half2_rn(Whh[row * 256 + kb], Whh[row * 256 + kb + 1]));
}

// ---------------------------------------------------------------------------
// Segment builder, two buckets: long segments (scan-len >= 6) compacted at
// queue[0..], short at queue[16384..]. Long-first popping lets the rest of
// the chip absorb short work while the longest serial chains run.
// Entry = (b<<19)|(start<<10)|len; valid iff start==0 or len>=2.
// ---------------------------------------------------------------------------
__global__ __launch_bounds__(512)
void seg_build(const int* __restrict__ masks, int* __restrict__ queue,
               int* __restrict__ qctl)
{
    __shared__ int sc[512];
    __shared__ int starts[512];
    __shared__ int cshr[3];
    const int b = blockIdx.x, s = threadIdx.x;
    const int is = (s == 0) || (masks[b * (T_ - 1) + s - 1] == 0);
    sc[s] = is;
    __syncthreads();
    #pragma unroll
    for (int off = 1; off < 512; off <<= 1) {
        int v = (s >= off) ? sc[s - off] : 0;
        __syncthreads();
        sc[s] += v;
        __syncthreads();
    }
    if (is) starts[sc[s] - 1] = s;
    if (s == 511) cshr[0] = sc[511];
    __syncthreads();
    const int cnt = cshr[0];
    int vL = 0, vS = 0, st = 0, ln = 0;
    if (s < cnt) {
        st = starts[s];
        const int nxt = (s + 1 < cnt) ? starts[s + 1] : T_;
        ln = nxt - st;
        if (st == 0 || ln >= 2) {
            const int scanlen = (st == 0) ? ln : ln - 1;
            if (scanlen >= 6) vL = 1; else vS = 1;
        }
    }
    __syncthreads();
    sc[s] = vL;
    __syncthreads();
    #pragma unroll
    for (int off = 1; off < 512; off <<= 1) {
        int v = (s >= off) ? sc[s - off] : 0;
        __syncthreads();
        sc[s] += v;
        __syncthreads();
    }
    const int pL = sc[s];
    if (s == 511) cshr[1] = atomicAdd(&qctl[0], sc[511]);
    __syncthreads();
    sc[s] = vS;
    __syncthreads();
    #pragma unroll
    for (int off = 1; off < 512; off <<= 1) {
        int v = (s >= off) ? sc[s - off] : 0;
        __syncthreads();
        sc[s] += v;
        __syncthreads();
    }
    const int pS = sc[s];
    if (s == 511) cshr[2] = atomicAdd(&qctl[2], sc[511]);
    __syncthreads();
    const int e = (b << 19) | (st << 10) | ln;
    if (vL) queue[cshr[1] + pL - 1] = e;
    if (vS) queue[16384 + cshr[2] + pS - 1] = e;
}

// ---------------------------------------------------------------------------
// Pre-pass (unchanged, passed r4/r6): every t>=1 with mask==0 has h_prev==0.
// ---------------------------------------------------------------------------
__global__ __launch_bounds__(256)
void h0pre(const __half* __restrict__ gx, const float* __restrict__ bhh,
           const int* __restrict__ masks, uint32_t* __restrict__ hs2)
{
    const int row = blockIdx.x;                 // 0 .. B*(T-1)-1
    if (masks[row] != 0) return;
    const int b = row / (T_ - 1), t = 1 + row - b * (T_ - 1);
    const int e = threadIdx.x;
    const __half* grow = gx + (size_t)(b * T_ + t) * 768;
    const float gxr = __half2float(grow[e]);
    const float gxz = __half2float(grow[e + 256]);
    const float gxn = __half2float(grow[e + 512]);
    const float rg = 1.f / (1.f + exp2f(-(gxr + bhh[e]) * 1.44269504f));
    const float zg = 1.f / (1.f + exp2f(-(gxz + bhh[e + 256]) * 1.44269504f));
    const float nin = gxn + rg * bhh[e + 512];
    const float e2x = exp2f(nin * 2.885390082f);
    const float ng = 1.f - 2.f / (e2x + 1.f);
    const float hnew = (1.f - zg) * ng;         // h_prev = 0
    const float other = __shfl_xor(hnew, 1);
    if (!(e & 1)) hs2[(size_t)(b * T_ + t) * 128 + (e >> 1)] = h2u(__floats2half2_rn(hnew, other));
}

// ---------------------------------------------------------------------------
// MFMA slot-parallel GRU, 2-barrier schedule + global work-stealing queue.
// 256 blocks x 512 threads (1/CU; regs cap at 2 waves/SIMD), 16 slots/block.
// Phase X: per-thread gx loads (consumed next phase, survive the barrier via
// lgkmcnt-only waitcnt) + gh[768x16] = W_hh x H (48 MFMA/wave, W_hh in 192
// AGPR A-frags) -> Pl. Phase Y: gates; advance or pop-refill (atomic pop by
// one lane, __shfl register broadcast -- no cross-wave LDS handoff).
// All cross-wave LDS producer/consumer pairs separated by lgkmcnt(0)+barrier.
// Seeds read only h0 / h0pre-written hs2 rows -- never scan-written rows.
// ---------------------------------------------------------------------------
__global__ __launch_bounds__(512, 2)
void gru_mfma(const __half* __restrict__ gx, const uint32_t* __restrict__ WhhP,
              const float* __restrict__ bhh, const float* __restrict__ h0,
              const int* __restrict__ queue, int* __restrict__ qctl,
              uint32_t* __restrict__ hs2)
{
    __shared__ __align__(16) __half Hl[NSLOT * 256];   // [slot][k], granule-swizzled
    __shared__ __align__(16) float  Pl[NSLOT * 780];   // [slot][row + pad]
    __shared__ float Bl[G_];
    __shared__ int s_t[NSLOT], s_end[NSLOT], s_row[NSLOT], s_act[NSLOT];

    const int tid = threadIdx.x;
    const int lane = tid & 63, w = tid >> 6;
    const int s = tid >> 5, g32 = tid & 31, e0 = g32 * 8;
    const int col = lane & 15, lq = lane >> 4;

    // ---- W_hh fragments: 48 contiguous f16x8 per lane (AGPR-resident) ----
    f16x8 wfrag[6][8];
    {
        const f16x8* wp = (const f16x8*)(WhhP + (size_t)tid * 192);
        #pragma unroll
        for (int i = 0; i < 6; ++i)
            #pragma unroll
            for (int c = 0; c < 8; ++c)
                wfrag[i][c] = wp[i * 8 + c];
    }
    if (tid < 384) { Bl[tid] = bhh[tid]; Bl[tid + 384] = bhh[tid + 384]; }
    {
        const uint4 z4 = {0u, 0u, 0u, 0u};
        *(uint4*)((char*)Hl + tid * 16) = z4;
    }
    const int NL = qctl[0];
    const int NQ = NL + qctl[2];
    int* qhead = qctl + 1;

    float hv[8] = {0.f, 0.f, 0.f, 0.f, 0.f, 0.f, 0.f, 0.f};

    // pop + seed slot s (group-parallel; entry broadcast via __shfl)
    auto refill = [&]() {
        int eloc = -1;
        if (g32 == 0) {
            const int p = atomicAdd(qhead, 1);
            if (p < NQ) eloc = (p < NL) ? queue[p] : queue[16384 + (p - NL)];
        }
        const int e = __shfl(eloc, lane & 32, 64);
        if (e >= 0) {
            const int ln = e & 1023, st = (e >> 10) & 511, nb = e >> 19;
            uint4 hseed;
            if (st == 0) {                               // batch-initial: h from h0
                const float4 a = *(const float4*)(h0 + nb * 256 + e0);
                const float4 b2 = *(const float4*)(h0 + nb * 256 + e0 + 4);
                hv[0] = a.x; hv[1] = a.y; hv[2] = a.z; hv[3] = a.w;
                hv[4] = b2.x; hv[5] = b2.y; hv[6] = b2.z; hv[7] = b2.w;
                hseed = cvt8(a, b2);
                if (g32 == 0) { s_t[s] = 0; s_end[s] = ln; s_row[s] = nb * T_; }
            } else {                                     // seed = h0pre output at start step
                hseed = *(const uint4*)(hs2 + (size_t)(nb * T_ + st) * 128 + g32 * 4);
                const __half2 p0 = u2h(hseed.x), p1 = u2h(hseed.y);
                const __half2 p2 = u2h(hseed.z), p3 = u2h(hseed.w);
                hv[0] = __low2float(p0); hv[1] = __high2float(p0);
                hv[2] = __low2float(p1); hv[3] = __high2float(p1);
                hv[4] = __low2float(p2); hv[5] = __high2float(p2);
                hv[6] = __low2float(p3); hv[7] = __high2float(p3);
                if (g32 == 0) { s_t[s] = st + 1; s_end[s] = st + ln; s_row[s] = nb * T_ + st + 1; }
            }
            *(uint4*)((char*)Hl + s * 512 + ((g32 ^ (s & 7)) << 4)) = hseed;
        } else if (g32 == 0) {
            s_act[s] = 0;
        }
    };

    if (g32 == 0) s_act[s] = 1;
    refill();                                            // initial fill (all groups)
    __syncthreads();

    for (;;) {
        bool alive = false;
        #pragma unroll
        for (int i = 0; i < NSLOT; ++i) alive |= (s_act[i] != 0);
        if (!alive) break;

        // ---- phase X: own-slot gx loads (used in Y; survive the barrier) ----
        const int myrow = s_row[s];
        const __half* grow = gx + (size_t)myrow * G_;
        const f16x8 gr = *(const f16x8*)(grow + e0);
        const f16x8 gz = *(const f16x8*)(grow + 256 + e0);
        const f16x8 gn = *(const f16x8*)(grow + 512 + e0);

        // MFMA: gh = W_hh x H
        f32x4 acc[6];
        #pragma unroll
        for (int i = 0; i < 6; ++i) { f32x4 z = {0.f, 0.f, 0.f, 0.f}; acc[i] = z; }
        #pragma unroll
        for (int c = 0; c < 8; ++c) {
            const f16x8 bf = *(const f16x8*)((const char*)Hl + col * 512 +
                                             ((((c << 2) + lq) ^ (col & 7)) << 4));
            #pragma unroll
            for (int i = 0; i < 6; ++i)
                acc[i] = __builtin_amdgcn_mfma_f32_16x16x32_f16(wfrag[i][c], bf, acc[i], 0, 0, 0);
        }
        #pragma unroll
        for (int i = 0; i < 6; ++i)
            *(f32x4*)(Pl + col * 780 + (w * 96 + i * 16 + lq * 4)) = acc[i];
        asm volatile("s_waitcnt lgkmcnt(0)" ::: "memory");  // drain LDS only; gx stays in flight
        __builtin_amdgcn_s_barrier();

        // ---- phase Y: gates, advance-or-refill ----
        if (s_act[s]) {
            const float* Pr = Pl + s * 780;
            const f32x4 R0 = *(const f32x4*)(Pr + e0),       R1 = *(const f32x4*)(Pr + e0 + 4);
            const f32x4 Z0 = *(const f32x4*)(Pr + 256 + e0), Z1 = *(const f32x4*)(Pr + 256 + e0 + 4);
            const f32x4 N0 = *(const f32x4*)(Pr + 512 + e0), N1 = *(const f32x4*)(Pr + 512 + e0 + 4);
            const f32x4 br0 = *(const f32x4*)(Bl + e0),       br1 = *(const f32x4*)(Bl + e0 + 4);
            const f32x4 bz0 = *(const f32x4*)(Bl + 256 + e0), bz1 = *(const f32x4*)(Bl + 256 + e0 + 4);
            const f32x4 bn0 = *(const f32x4*)(Bl + 512 + e0), bn1 = *(const f32x4*)(Bl + 512 + e0 + 4);
            float hn[8];
            #pragma unroll
            for (int j = 0; j < 8; ++j) {
                const float ghr = (j < 4 ? R0[j] : R1[j - 4]) + (j < 4 ? br0[j] : br1[j - 4]);
                const float ghz = (j < 4 ? Z0[j] : Z1[j - 4]) + (j < 4 ? bz0[j] : bz1[j - 4]);
                const float ghn = (j < 4 ? N0[j] : N1[j - 4]) + (j < 4 ? bn0[j] : bn1[j - 4]);
                const float rg = 1.f / (1.f + exp2f(-((float)gr[j] + ghr) * 1.44269504f));
                const float zg = 1.f / (1.f + exp2f(-((float)gz[j] + ghz) * 1.44269504f));
                const float nin = (float)gn[j] + rg * ghn;
                const float ex = exp2f(nin * 2.885390082f);
                const float ng = 1.f - 2.f / (ex + 1.f);
                hn[j] = (1.f - zg) * ng + zg * hv[j];
                hv[j] = hn[j];
            }
            uint4 hp;
            hp.x = h2u(__floats2half2_rn(hn[0], hn[1]));
            hp.y = h2u(__floats2half2_rn(hn[2], hn[3]));
            hp.z = h2u(__floats2half2_rn(hn[4], hn[5]));
            hp.w = h2u(__floats2half2_rn(hn[6], hn[7]));
            *(uint4*)(hs2 + (size_t)myrow * 128 + g32 * 4) = hp;
            if (s_t[s] + 1 < s_end[s]) {                 // continue this segment
                *(uint4*)((char*)Hl + s * 512 + ((g32 ^ (s & 7)) << 4)) = hp;
                if (g32 == 0) { s_t[s]++; s_row[s]++; }
            } else {                                     // done -> pop next
                refill();
            }
        }
        asm volatile("s_waitcnt lgkmcnt(0)" ::: "memory");
        __builtin_amdgcn_s_barrier();
    }
}

// ---------------------------------------------------------------------------
// Heads (unchanged, passed): one wave per output row, hs fp16.
// ---------------------------------------------------------------------------
__global__ __launch_bounds__(256)
void heads_kernel(const uint32_t* __restrict__ hs2, const float* __restrict__ Wa,
                  const float* __restrict__ ba, const float* __restrict__ Wc,
                  const float* __restrict__ bc, const int* __restrict__ action,
                  float* __restrict__ out)
{
    const int wid = threadIdx.x >> 6, lane = threadIdx.x & 63;
    const int row = blockIdx.x * 4 + wid;
    const uint2 hv2 = ((const uint2*)(hs2 + (size_t)row * 128))[lane];
    const __half2 ha = u2h(hv2.x), hb = u2h(hv2.y);
    const float h0f = __low2float(ha), h1f = __high2float(ha);
    const float h2f = __low2float(hb), h3f = __high2float(hb);
    float sums[11];
    #pragma unroll
    for (int n = 0; n < 11; ++n) {
        const float* wrow = (n < 10) ? (Wa + n * 256) : Wc;
        const float4 wv = ((const float4*)wrow)[lane];
        sums[n] = h0f * wv.x + h1f * wv.y + h2f * wv.z + h3f * wv.w;
    }
    #pragma unroll
    for (int n = 0; n < 11; ++n) {
        float v = sums[n];
        #pragma unroll
        for (int off = 32; off; off >>= 1) v += __shfl_xor(v, off);
        sums[n] = v;
    }
    float logits[10];
    #pragma unroll
    for (int n = 0; n < 10; ++n) logits[n] = sums[n] + ba[n];
    const float value = sums[10] + bc[0];
    float mx = logits[0];
    #pragma unroll
    for (int n = 1; n < 10; ++n) mx = fmaxf(mx, logits[n]);
    float ssum = 0.f, sdot = 0.f;
    #pragma unroll
    for (int n = 0; n < 10; ++n) {
        float d = logits[n] - mx;
        float e = exp2f(d * 1.44269504f);
        ssum += e; sdot += e * d;
    }
    const float lns = logf(ssum);
    const float lse = mx + lns;
    const float entropy = lns - sdot / ssum;
    const int a = action[row];
    float la = 0.f;
    #pragma unroll
    for (int n = 0; n < 10; ++n) la = (n == a) ? logits[n] : la;
    if (lane == 0) {
        out[row] = value;
        out[BT_ + row] = la - lse;
        out[2 * BT_ + row] = entropy;
    }
}

// ---------------------------------------------------------------------------
extern "C" void kernel_launch(void* const* d_in, const int* in_sizes, int n_in,
                              void* d_out, int out_size, void* d_ws, size_t ws_size,
                              hipStream_t stream)
{
    const float* obs    = (const float*)d_in[0];
    const int*   action = (const int*)d_in[1];
    const int*   masks  = (const int*)d_in[2];
    const float* h0     = (const float*)d_in[3];
    const float* W1     = (const float*)d_in[4];
    const float* b1     = (const float*)d_in[5];
    const float* Wih    = (const float*)d_in[6];
    const float* Whh    = (const float*)d_in[7];
    const float* bih    = (const float*)d_in[8];
    const float* bhh    = (const float*)d_in[9];
    const float* Wa     = (const float*)d_in[10];
    const float* ba     = (const float*)d_in[11];
    const float* Wc     = (const float*)d_in[12];
    const float* bc     = (const float*)d_in[13];
    float* out = (float*)d_out;

    char* p = (char*)d_ws;
    __half*   feat = (__half*)p;    p += (size_t)BT_ * FEAT_ * 2;   // 33.6 MB
    __half*   gx   = (__half*)p;    p += (size_t)BT_ * G_ * 2;      // 50.3 MB
    uint32_t* hs2  = (uint32_t*)p;  p += (size_t)BT_ * H_ * 2;      // 16.8 MB
    uint32_t* W1h  = (uint32_t*)p;  p += FEAT_ * OBS_ * 2;          // 131 KB
    uint32_t* Wihh = (uint32_t*)p;  p += G_ * FEAT_ * 2;            // 786 KB
    uint32_t* WhhP = (uint32_t*)p;  p += 512 * 192 * 4;             // 393 KB
    int*      queue= (int*)p;       p += 32768 * 4;                 // two 16384 buckets
    int*      qctl = (int*)p;       p += 256;                       // [0]=longN,[1]=head,[2]=shortN

    // packs (pack_whh zeroes qctl) + bucketed segment queue build
    pack_half<<<(FEAT_ * OBS_ / 2 + 255) / 256, 256, 0, stream>>>(W1, W1h, FEAT_ * OBS_ / 2);
    pack_half<<<(G_ * FEAT_ / 2 + 255) / 256, 256, 0, stream>>>(Wih, Wihh, G_ * FEAT_ / 2);
    pack_whh<<<384, 256, 0, stream>>>(Whh, WhhP, qctl);
    seg_build<<<B_, 512, 0, stream>>>(masks, queue, qctl);
    // feat = relu(obs @ W1^T + b1)
    mfma_gemm<OBS_, true, true><<<dim3(256, 4), 256, 0, stream>>>(obs, nullptr, (const __half*)W1h, b1, (uint32_t*)feat, FEAT_);
    // gx = feat @ W_ih^T + b_ih   (batch-major rows)
    mfma_gemm<FEAT_, false, false><<<dim3(256, 6), 256, 0, stream>>>(nullptr, feat, (const __half*)Wihh, bih, (uint32_t*)gx, G_);
    // pre-pass: all h_prev==0 steps (elementwise)
    h0pre<<<B_ * (T_ - 1), 256, 0, stream>>>(gx, bhh, masks, hs2);
    // MFMA slot-parallel recurrence (global queue, longest-first, 2 barriers/iter)
    gru_mfma<<<256, 512, 0, stream>>>(gx, WhhP, bhh, h0, queue, qctl, hs2);
    // heads
    heads_kernel<<<8192, 256, 0, stream>>>(hs2, Wa, ba, Wc, bc, action, out);
}

// Round 8
// 229.761 us; speedup vs baseline: 1.3170x; 1.3170x over previous
//
#include <hip/hip_runtime.h>
#include <hip/hip_fp16.h>
#include <stdint.h>

#define B_    64
#define T_    512
#define OBS_  128
#define FEAT_ 512
#define H_    256
#define G_    768
#define BT_   32768
#define NSLOT 16

typedef _Float16 f16x8 __attribute__((ext_vector_type(8)));
typedef float    f32x4 __attribute__((ext_vector_type(4)));

__device__ __forceinline__ uint32_t h2u(__half2 h){ union{ __half2 h; uint32_t u; } c; c.h = h; return c.u; }
__device__ __forceinline__ __half2 u2h(uint32_t u){ union{ uint32_t u; __half2 h; } c; c.u = u; return c.h; }

// swizzled LDS byte offset for GEMM tiles: [128 rows][8 chunks of 16B], chunk ^= row&7
__device__ __forceinline__ int sw(int r, int c) { return r * 128 + ((c ^ (r & 7)) << 4); }

__device__ __forceinline__ uint4 cvt8(float4 a, float4 b) {
    uint4 u;
    u.x = h2u(__floats2half2_rn(a.x, a.y));
    u.y = h2u(__floats2half2_rn(a.z, a.w));
    u.z = h2u(__floats2half2_rn(b.x, b.y));
    u.w = h2u(__floats2half2_rn(b.z, b.w));
    return u;
}

// ---------------------------------------------------------------------------
// MFMA GEMM: C[M x N](fp16) = act( A[M x K] @ W[N x K]^T + bias )
// 128x128 tile, BK=64, 4 waves (2x2), each wave 4x4 frags of 16x16x32_f16.
// (unchanged -- passed r3/r4/r6/r7)
// ---------------------------------------------------------------------------
template<int KD, bool AF32, bool RELU>
__global__ __launch_bounds__(256, 2)
void mfma_gemm(const float* __restrict__ Af, const __half* __restrict__ Ah,
               const __half* __restrict__ Bh, const float* __restrict__ bias,
               uint32_t* __restrict__ C, int N)
{
    __shared__ __align__(16) __half As[128 * 64];
    __shared__ __align__(16) __half Bs[128 * 64];
    const int m0 = blockIdx.x * 128, n0 = blockIdx.y * 128;
    const int tid = threadIdx.x;
    const int r = tid >> 1, cb = (tid & 1) * 4;
    const int lane = tid & 63, w = tid >> 6;
    const int wm = w >> 1, wn = w & 1;
    const int l15 = lane & 15, lq = lane >> 4;
    constexpr int KT = KD / 64;

    f32x4 acc[4][4];
    #pragma unroll
    for (int i = 0; i < 4; ++i)
        #pragma unroll
        for (int j = 0; j < 4; ++j) {
            f32x4 z = {0.f, 0.f, 0.f, 0.f};
            acc[i][j] = z;
        }

    uint4 sa[4], sb[4];
    float4 sa32[8];

    auto loads = [&](int kt) {
        if constexpr (AF32) {
            const float* ap = Af + (size_t)(m0 + r) * KD + kt * 64 + cb * 8;
            #pragma unroll
            for (int c = 0; c < 4; ++c) {
                sa32[2 * c]     = ((const float4*)ap)[2 * c];
                sa32[2 * c + 1] = ((const float4*)ap)[2 * c + 1];
            }
        } else {
            const __half* ap = Ah + (size_t)(m0 + r) * KD + kt * 64 + cb * 8;
            #pragma unroll
            for (int c = 0; c < 4; ++c) sa[c] = ((const uint4*)ap)[c];
        }
        const __half* bp = Bh + (size_t)(n0 + r) * KD + kt * 64 + cb * 8;
        #pragma unroll
        for (int c = 0; c < 4; ++c) sb[c] = ((const uint4*)bp)[c];
    };

    auto dswrite = [&]() {
        #pragma unroll
        for (int c = 0; c < 4; ++c) {
            uint4 va;
            if constexpr (AF32) va = cvt8(sa32[2 * c], sa32[2 * c + 1]);
            else                va = sa[c];
            *(uint4*)((char*)As + sw(r, cb + c)) = va;
            *(uint4*)((char*)Bs + sw(r, cb + c)) = sb[c];
        }
    };

    auto compute = [&]() {
        #pragma unroll
        for (int kc = 0; kc < 2; ++kc) {
            f16x8 af[4], bf[4];
            #pragma unroll
            for (int mi = 0; mi < 4; ++mi)
                af[mi] = *(const f16x8*)((const char*)As + sw(wm * 64 + mi * 16 + l15, kc * 4 + lq));
            #pragma unroll
            for (int ni = 0; ni < 4; ++ni)
                bf[ni] = *(const f16x8*)((const char*)Bs + sw(wn * 64 + ni * 16 + l15, kc * 4 + lq));
            #pragma unroll
            for (int mi = 0; mi < 4; ++mi)
                #pragma unroll
                for (int ni = 0; ni < 4; ++ni)
                    acc[mi][ni] = __builtin_amdgcn_mfma_f32_16x16x32_f16(af[mi], bf[ni], acc[mi][ni], 0, 0, 0);
        }
    };

    loads(0);
    for (int kt = 0; kt < KT; ++kt) {
        __syncthreads();
        dswrite();
        __syncthreads();
        if (kt + 1 < KT) loads(kt + 1);
        compute();
    }

    #pragma unroll
    for (int ni = 0; ni < 4; ++ni) {
        const int col = n0 + wn * 64 + ni * 16 + l15;
        const float bv = bias[col];
        #pragma unroll
        for (int mi = 0; mi < 4; ++mi) {
            f32x4 d = acc[mi][ni];
            #pragma unroll
            for (int rr = 0; rr < 4; ++rr) {
                float v = d[rr] + bv;
                if (RELU) v = fmaxf(v, 0.0f);
                uint32_t u = (uint32_t)__half_as_ushort(__float2half(v));
                uint32_t nb = (uint32_t)__shfl_xor((int)u, 1);
                if (!(lane & 1)) {
                    const int row = m0 + wm * 64 + mi * 16 + lq * 4 + rr;
                    C[(size_t)row * (N >> 1) + (col >> 1)] = u | (nb << 16);
                }
            }
        }
    }
}

// ---------------------------------------------------------------------------
// Weight packs. pack_whh zeroes qctl and splits W_hh into:
//   WhhR: per-thread regs, K-chunks 0..5 (36 uint4/thread, contiguous)
//   WhhL: frag-major [12][512] uint4, K-chunks 6..7 (block copies into LDS)
// Fragment map: thread t=w*64+lane -> rows w*96+i*16+(lane&15),
// k = c*32+(lane>>4)*8+j.
// ---------------------------------------------------------------------------
__global__ void pack_half(const float* __restrict__ in, uint32_t* __restrict__ out, int n2)
{
    int i = blockIdx.x * 256 + threadIdx.x;
    if (i < n2) {
        float2 f = ((const float2*)in)[i];
        out[i] = h2u(__floats2half2_rn(f.x, f.y));
    }
}

__global__ void pack_whh(const float* __restrict__ Whh, uint32_t* __restrict__ outR,
                         uint32_t* __restrict__ outL, int* __restrict__ qctl)
{
    if (blockIdx.x == 0 && threadIdx.x == 0) { qctl[0] = 0; qctl[1] = 0; }
    int p = blockIdx.x * 256 + threadIdx.x;
    if (p >= 512 * 192) return;
    const int v4 = p >> 2, sub = p & 3;
    const int t = v4 / 48, ic = v4 - t * 48;
    const int i = ic >> 3, c = ic & 7;
    const int w = t >> 6, lane = t & 63;
    const int row = w * 96 + i * 16 + (lane & 15);
    const int kb = c * 32 + ((lane >> 4) << 3) + sub * 2;
    const uint32_t val = h2u(__floats2half2_rn(Whh[row * 256 + kb], Whh[row * 256 + kb + 1]));
    if (c < 6) outR[(t * 36 + i * 6 + c) * 4 + sub] = val;
    else       outL[(((i << 1) + (c - 6)) * 512 + t) * 4 + sub] = val;
}

// ---------------------------------------------------------------------------
// Segment builder (r6-proven, single bucket, batch-major order so static
// slices are statistically balanced). Entry = (b<<19)|(start<<10)|len;
// valid iff start==0 (h0 seed) or len>=2 (len-1 ones fully done by h0pre).
// ---------------------------------------------------------------------------
__global__ __launch_bounds__(512)
void seg_build(const int* __restrict__ masks, int* __restrict__ queue,
               int* __restrict__ qtail)
{
    __shared__ int sc[512];
    __shared__ int starts[512];
    __shared__ int cshr[2];
    const int b = blockIdx.x, s = threadIdx.x;
    const int is = (s == 0) || (masks[b * (T_ - 1) + s - 1] == 0);
    sc[s] = is;
    __syncthreads();
    #pragma unroll
    for (int off = 1; off < 512; off <<= 1) {
        int v = (s >= off) ? sc[s - off] : 0;
        __syncthreads();
        sc[s] += v;
        __syncthreads();
    }
    if (is) starts[sc[s] - 1] = s;
    if (s == 511) cshr[0] = sc[511];
    __syncthreads();
    const int cnt = cshr[0];
    int valid = 0, st = 0, ln = 0;
    if (s < cnt) {
        st = starts[s];
        const int nxt = (s + 1 < cnt) ? starts[s + 1] : T_;
        ln = nxt - st;
        valid = (st == 0 || ln >= 2) ? 1 : 0;
    }
    sc[s] = valid;
    __syncthreads();
    #pragma unroll
    for (int off = 1; off < 512; off <<= 1) {
        int v = (s >= off) ? sc[s - off] : 0;
        __syncthreads();
        sc[s] += v;
        __syncthreads();
    }
    if (s == 511) cshr[1] = atomicAdd(qtail, sc[511]);
    __syncthreads();
    if (valid) queue[cshr[1] + sc[s] - 1] = (b << 19) | (st << 10) | ln;
}

// ---------------------------------------------------------------------------
// Pre-pass, grid-stride: every t>=1 with mask==0 has h_prev==0.
// ---------------------------------------------------------------------------
__global__ __launch_bounds__(256)
void h0pre(const __half* __restrict__ gx, const float* __restrict__ bhh,
           const int* __restrict__ masks, uint32_t* __restrict__ hs2)
{
    for (int row = blockIdx.x; row < B_ * (T_ - 1); row += gridDim.x) {
        if (masks[row] != 0) continue;
        const int b = row / (T_ - 1), t = 1 + row - b * (T_ - 1);
        const int e = threadIdx.x;
        const __half* grow = gx + (size_t)(b * T_ + t) * 768;
        const float gxr = __half2float(grow[e]);
        const float gxz = __half2float(grow[e + 256]);
        const float gxn = __half2float(grow[e + 512]);
        const float rg = 1.f / (1.f + exp2f(-(gxr + bhh[e]) * 1.44269504f));
        const float zg = 1.f / (1.f + exp2f(-(gxz + bhh[e + 256]) * 1.44269504f));
        const float nin = gxn + rg * bhh[e + 512];
        const float e2x = exp2f(nin * 2.885390082f);
        const float ng = 1.f - 2.f / (e2x + 1.f);
        const float hnew = (1.f - zg) * ng;     // h_prev = 0
        const float other = __shfl_xor(hnew, 1);
        if (!(e & 1)) hs2[(size_t)(b * T_ + t) * 128 + (e >> 1)] = h2u(__floats2half2_rn(hnew, other));
    }
}

// ---------------------------------------------------------------------------
// MFMA slot-parallel GRU v3. 256 blocks x 512 threads (1/CU), 16 slots/block,
// static queue slices + LDS cursor (r6-proven scheduling; r7's global steal
// regressed). W_hh: 36 frags in regs (144) + 12 frags in LDS (98KB) so peak
// register demand ~230 < 256 -- the r6/r7 versions demanded ~290, forcing the
// compiler to re-fetch weights from L2 every iteration (the 14K cy/iter
// mystery). 2 raw barriers/iter (lgkmcnt-only: gx + seed loads stay in
// flight). Next segment pre-popped at segment start; its seed loads issue in
// phase X and land in registers before the segment ends. h_prev re-read from
// Hl (fp16, same math). Seeds only read h0 / h0pre rows -- never scan rows.
// ---------------------------------------------------------------------------
__global__ __launch_bounds__(512, 2)
void gru_mfma(const __half* __restrict__ gx, const uint4* __restrict__ WhhR,
              const uint4* __restrict__ WhhL, const float* __restrict__ bhh,
              const float* __restrict__ h0, const int* __restrict__ queue,
              const int* __restrict__ qctl, uint32_t* __restrict__ hs2)
{
    __shared__ __align__(16) __half Hl[NSLOT * 256];   // 8KB, granule-swizzled
    __shared__ __align__(16) __half Plh[NSLOT * 784];  // 24.5KB gh (fp16)
    __shared__ __align__(16) uint4  Wl[12 * 512];      // 98KB W_hh K-chunks 6..7
    __shared__ float Bl[G_];
    __shared__ int s_end[NSLOT], s_row[NSLOT], s_act[NSLOT], s_nxt[NSLOT];
    __shared__ int cur;

    const int tid = threadIdx.x;
    const int lane = tid & 63, w = tid >> 6;
    const int s = tid >> 5, g32 = tid & 31, e0 = g32 * 8;
    const int col = lane & 15, lq = lane >> 4;

    // W_hh register fragments (chunks 0..5): 36 contiguous uint4 per thread
    f16x8 wr[36];
    {
        const f16x8* wp = (const f16x8*)(WhhR + (size_t)tid * 36);
        #pragma unroll
        for (int i = 0; i < 36; ++i) wr[i] = wp[i];
    }
    // W_hh LDS fragments (chunks 6..7), frag-major -> contiguous reads
    #pragma unroll
    for (int i = 0; i < 12; ++i) Wl[i * 512 + tid] = WhhL[i * 512 + tid];
    if (tid < 384) { Bl[tid] = bhh[tid]; Bl[tid + 384] = bhh[tid + 384]; }
    { const uint4 z4 = {0u, 0u, 0u, 0u}; *(uint4*)((char*)Hl + tid * 16) = z4; }

    const int NQ = qctl[0];
    const int gb = blockIdx.x;
    const int lo = (int)(((long long)NQ * gb) >> 8);
    const int hi = (int)(((long long)NQ * (gb + 1)) >> 8);
    if (tid == 0) cur = lo + NSLOT;
    __syncthreads();

    // ---- preamble: seed initial slots; pre-pop one entry per active slot ----
    {
        int e = -1;
        if (lo + s < hi) e = queue[lo + s];
        if (e >= 0) {
            const int ln = e & 1023, st = (e >> 10) & 511, nb = e >> 19;
            uint4 hseed;
            if (st == 0) {
                const float4 a = *(const float4*)(h0 + nb * 256 + e0);
                const float4 b = *(const float4*)(h0 + nb * 256 + e0 + 4);
                hseed = cvt8(a, b);
                if (g32 == 0) { s_row[s] = nb * T_; s_end[s] = nb * T_ + ln; }
            } else {
                hseed = *(const uint4*)(hs2 + (size_t)(nb * T_ + st) * 128 + g32 * 4);
                if (g32 == 0) { s_row[s] = nb * T_ + st + 1; s_end[s] = nb * T_ + st + ln; }
            }
            *(uint4*)((char*)Hl + s * 512 + ((g32 ^ (s & 7)) << 4)) = hseed;
            if (g32 == 0) {
                s_act[s] = 1;
                const int p = atomicAdd(&cur, 1);
                s_nxt[s] = (p < hi) ? queue[p] : -1;
            }
        } else if (g32 == 0) {
            s_act[s] = 0; s_nxt[s] = -1; s_row[s] = 0; s_end[s] = 0;
        }
    }
    __syncthreads();

    for (;;) {
        bool alive = false;
        #pragma unroll
        for (int i = 0; i < NSLOT; ++i) alive |= (s_act[i] != 0);
        if (!alive) break;

        // ---- phase X ----
        const int myrow = s_row[s];
        const int nxte = s_nxt[s];
        // gx for the current step (consumed in Y; survives barrier)
        const __half* grow = gx + (size_t)myrow * G_;
        const f16x8 gr = *(const f16x8*)(grow + e0);
        const f16x8 gz = *(const f16x8*)(grow + 256 + e0);
        const f16x8 gn = *(const f16x8*)(grow + 512 + e0);
        // seed prefetch for the next segment (consumed in Y at segment end)
        uint4 su = {0u, 0u, 0u, 0u};
        if (nxte >= 0) {
            const int st = (nxte >> 10) & 511, nb = nxte >> 19;
            if (st == 0) {
                const float4 a = *(const float4*)(h0 + nb * 256 + e0);
                const float4 b = *(const float4*)(h0 + nb * 256 + e0 + 4);
                su = cvt8(a, b);
            } else {
                su = *(const uint4*)(hs2 + (size_t)(nb * T_ + st) * 128 + g32 * 4);
            }
        }
        // MFMA: gh = W_hh x H (36 reg-frags + 12 LDS-frags)
        f16x8 bfv[8];
        #pragma unroll
        for (int c = 0; c < 8; ++c)
            bfv[c] = *(const f16x8*)((const char*)Hl + col * 512 +
                                     ((((c << 2) + lq) ^ (col & 7)) << 4));
        f32x4 acc[6];
        #pragma unroll
        for (int i = 0; i < 6; ++i) { const f32x4 z = {0.f, 0.f, 0.f, 0.f}; acc[i] = z; }
        #pragma unroll
        for (int c = 0; c < 6; ++c)
            #pragma unroll
            for (int i = 0; i < 6; ++i)
                acc[i] = __builtin_amdgcn_mfma_f32_16x16x32_f16(wr[i * 6 + c], bfv[c], acc[i], 0, 0, 0);
        #pragma unroll
        for (int c2 = 0; c2 < 2; ++c2)
            #pragma unroll
            for (int i = 0; i < 6; ++i) {
                const f16x8 wlt = *(const f16x8*)&Wl[(i * 2 + c2) * 512 + tid];
                acc[i] = __builtin_amdgcn_mfma_f32_16x16x32_f16(wlt, bfv[6 + c2], acc[i], 0, 0, 0);
            }
        #pragma unroll
        for (int i = 0; i < 6; ++i) {
            uint2 ph;
            ph.x = h2u(__floats2half2_rn(acc[i][0], acc[i][1]));
            ph.y = h2u(__floats2half2_rn(acc[i][2], acc[i][3]));
            *(uint2*)(Plh + col * 784 + (w * 96 + i * 16 + lq * 4)) = ph;
        }
        asm volatile("s_waitcnt lgkmcnt(0)" ::: "memory");  // LDS visible; vmem stays in flight
        __builtin_amdgcn_s_barrier();

        // ---- phase Y: gates, advance or start pre-popped segment ----
        if (s_act[s]) {
            const __half* Pr = Plh + s * 784;
            const f16x8 R  = *(const f16x8*)(Pr + e0);
            const f16x8 Z  = *(const f16x8*)(Pr + 256 + e0);
            const f16x8 Nn = *(const f16x8*)(Pr + 512 + e0);
            const f32x4 br0 = *(const f32x4*)(Bl + e0),       br1 = *(const f32x4*)(Bl + e0 + 4);
            const f32x4 bz0 = *(const f32x4*)(Bl + 256 + e0), bz1 = *(const f32x4*)(Bl + 256 + e0 + 4);
            const f32x4 bn0 = *(const f32x4*)(Bl + 512 + e0), bn1 = *(const f32x4*)(Bl + 512 + e0 + 4);
            const uint4 hp4 = *(const uint4*)((const char*)Hl + s * 512 + ((g32 ^ (s & 7)) << 4));
            const __half2 q0 = u2h(hp4.x), q1 = u2h(hp4.y), q2 = u2h(hp4.z), q3 = u2h(hp4.w);
            const float hpv[8] = { __low2float(q0), __high2float(q0), __low2float(q1), __high2float(q1),
                                   __low2float(q2), __high2float(q2), __low2float(q3), __high2float(q3) };
            float hn[8];
            #pragma unroll
            for (int j = 0; j < 8; ++j) {
                const float ghr = (float)R[j]  + (j < 4 ? br0[j] : br1[j - 4]);
                const float ghz = (float)Z[j]  + (j < 4 ? bz0[j] : bz1[j - 4]);
                const float ghn = (float)Nn[j] + (j < 4 ? bn0[j] : bn1[j - 4]);
                const float rg = 1.f / (1.f + exp2f(-((float)gr[j] + ghr) * 1.44269504f));
                const float zg = 1.f / (1.f + exp2f(-((float)gz[j] + ghz) * 1.44269504f));
                const float nin = (float)gn[j] + rg * ghn;
                const float ex = exp2f(nin * 2.885390082f);
                const float ng = 1.f - 2.f / (ex + 1.f);
                hn[j] = (1.f - zg) * ng + zg * hpv[j];
            }
            uint4 hp;
            hp.x = h2u(__floats2half2_rn(hn[0], hn[1]));
            hp.y = h2u(__floats2half2_rn(hn[2], hn[3]));
            hp.z = h2u(__floats2half2_rn(hn[4], hn[5]));
            hp.w = h2u(__floats2half2_rn(hn[6], hn[7]));
            *(uint4*)(hs2 + (size_t)myrow * 128 + g32 * 4) = hp;
            if (myrow + 1 < s_end[s]) {
                *(uint4*)((char*)Hl + s * 512 + ((g32 ^ (s & 7)) << 4)) = hp;
                if (g32 == 0) s_row[s] = myrow + 1;
            } else if (nxte >= 0) {          // start pre-popped segment
                const int ln = nxte & 1023, st = (nxte >> 10) & 511, nb = nxte >> 19;
                *(uint4*)((char*)Hl + s * 512 + ((g32 ^ (s & 7)) << 4)) = su;
                if (g32 == 0) {
                    if (st == 0) { s_row[s] = nb * T_;          s_end[s] = nb * T_ + ln; }
                    else         { s_row[s] = nb * T_ + st + 1; s_end[s] = nb * T_ + st + ln; }
                    const int p = atomicAdd(&cur, 1);
                    s_nxt[s] = (p < hi) ? queue[p] : -1;
                }
            } else if (g32 == 0) {
                s_act[s] = 0;
            }
        }
        asm volatile("s_waitcnt lgkmcnt(0)" ::: "memory");
        __builtin_amdgcn_s_barrier();
    }
}

// ---------------------------------------------------------------------------
// Heads (unchanged, passed): one wave per output row, hs fp16.
// ---------------------------------------------------------------------------
__global__ __launch_bounds__(256)
void heads_kernel(const uint32_t* __restrict__ hs2, const float* __restrict__ Wa,
                  const float* __restrict__ ba, const float* __restrict__ Wc,
                  const float* __restrict__ bc, const int* __restrict__ action,
                  float* __restrict__ out)
{
    const int wid = threadIdx.x >> 6, lane = threadIdx.x & 63;
    const int row = blockIdx.x * 4 + wid;
    const uint2 hv2 = ((const uint2*)(hs2 + (size_t)row * 128))[lane];
    const __half2 ha = u2h(hv2.x), hb = u2h(hv2.y);
    const float h0f = __low2float(ha), h1f = __high2float(ha);
    const float h2f = __low2float(hb), h3f = __high2float(hb);
    float sums[11];
    #pragma unroll
    for (int n = 0; n < 11; ++n) {
        const float* wrow = (n < 10) ? (Wa + n * 256) : Wc;
        const float4 wv = ((const float4*)wrow)[lane];
        sums[n] = h0f * wv.x + h1f * wv.y + h2f * wv.z + h3f * wv.w;
    }
    #pragma unroll
    for (int n = 0; n < 11; ++n) {
        float v = sums[n];
        #pragma unroll
        for (int off = 32; off; off >>= 1) v += __shfl_xor(v, off);
        sums[n] = v;
    }
    float logits[10];
    #pragma unroll
    for (int n = 0; n < 10; ++n) logits[n] = sums[n] + ba[n];
    const float value = sums[10] + bc[0];
    float mx = logits[0];
    #pragma unroll
    for (int n = 1; n < 10; ++n) mx = fmaxf(mx, logits[n]);
    float ssum = 0.f, sdot = 0.f;
    #pragma unroll
    for (int n = 0; n < 10; ++n) {
        float d = logits[n] - mx;
        float e = exp2f(d * 1.44269504f);
        ssum += e; sdot += e * d;
    }
    const float lns = logf(ssum);
    const float lse = mx + lns;
    const float entropy = lns - sdot / ssum;
    const int a = action[row];
    float la = 0.f;
    #pragma unroll
    for (int n = 0; n < 10; ++n) la = (n == a) ? logits[n] : la;
    if (lane == 0) {
        out[row] = value;
        out[BT_ + row] = la - lse;
        out[2 * BT_ + row] = entropy;
    }
}

// ---------------------------------------------------------------------------
extern "C" void kernel_launch(void* const* d_in, const int* in_sizes, int n_in,
                              void* d_out, int out_size, void* d_ws, size_t ws_size,
                              hipStream_t stream)
{
    const float* obs    = (const float*)d_in[0];
    const int*   action = (const int*)d_in[1];
    const int*   masks  = (const int*)d_in[2];
    const float* h0     = (const float*)d_in[3];
    const float* W1     = (const float*)d_in[4];
    const float* b1     = (const float*)d_in[5];
    const float* Wih    = (const float*)d_in[6];
    const float* Whh    = (const float*)d_in[7];
    const float* bih    = (const float*)d_in[8];
    const float* bhh    = (const float*)d_in[9];
    const float* Wa     = (const float*)d_in[10];
    const float* ba     = (const float*)d_in[11];
    const float* Wc     = (const float*)d_in[12];
    const float* bc     = (const float*)d_in[13];
    float* out = (float*)d_out;

    char* p = (char*)d_ws;
    __half*   feat = (__half*)p;    p += (size_t)BT_ * FEAT_ * 2;   // 33.6 MB
    __half*   gx   = (__half*)p;    p += (size_t)BT_ * G_ * 2;      // 50.3 MB
    uint32_t* hs2  = (uint32_t*)p;  p += (size_t)BT_ * H_ * 2;      // 16.8 MB
    uint32_t* W1h  = (uint32_t*)p;  p += FEAT_ * OBS_ * 2;          // 131 KB
    uint32_t* Wihh = (uint32_t*)p;  p += G_ * FEAT_ * 2;            // 786 KB
    uint4*    WhhR = (uint4*)p;     p += 512 * 36 * 16;             // 295 KB
    uint4*    WhhL = (uint4*)p;     p += 12 * 512 * 16;             // 98 KB
    int*      queue= (int*)p;       p += B_ * 512 * 4;              // 131 KB
    int*      qctl = (int*)p;       p += 256;                       // [0]=tail

    // packs (pack_whh zeroes qctl) + segment queue build
    pack_half<<<(FEAT_ * OBS_ / 2 + 255) / 256, 256, 0, stream>>>(W1, W1h, FEAT_ * OBS_ / 2);
    pack_half<<<(G_ * FEAT_ / 2 + 255) / 256, 256, 0, stream>>>(Wih, Wihh, G_ * FEAT_ / 2);
    pack_whh<<<384, 256, 0, stream>>>(Whh, (uint32_t*)WhhR, (uint32_t*)WhhL, qctl);
    seg_build<<<B_, 512, 0, stream>>>(masks, queue, &qctl[0]);
    // feat = relu(obs @ W1^T + b1)
    mfma_gemm<OBS_, true, true><<<dim3(256, 4), 256, 0, stream>>>(obs, nullptr, (const __half*)W1h, b1, (uint32_t*)feat, FEAT_);
    // gx = feat @ W_ih^T + b_ih   (batch-major rows)
    mfma_gemm<FEAT_, false, false><<<dim3(256, 6), 256, 0, stream>>>(nullptr, feat, (const __half*)Wihh, bih, (uint32_t*)gx, G_);
    // pre-pass: all h_prev==0 steps (elementwise, grid-stride)
    h0pre<<<2048, 256, 0, stream>>>(gx, bhh, masks, hs2);
    // MFMA slot-parallel recurrence (static slices, 2 barriers/iter, pre-pop)
    gru_mfma<<<256, 512, 0, stream>>>(gx, WhhR, WhhL, bhh, h0, queue, qctl, hs2);
    // heads
    heads_kernel<<<8192, 256, 0, stream>>>(hs2, Wa, ba, Wc, bc, action, out);
}

// Round 9
// 226.634 us; speedup vs baseline: 1.3352x; 1.0138x over previous
//
#include <hip/hip_runtime.h>
#include <hip/hip_fp16.h>
#include <stdint.h>

#define B_    64
#define T_    512
#define OBS_  128
#define FEAT_ 512
#define H_    256
#define G_    768
#define BT_   32768
#define NSLOT 16

typedef _Float16 f16x8 __attribute__((ext_vector_type(8)));
typedef float    f32x4 __attribute__((ext_vector_type(4)));

__device__ __forceinline__ uint32_t h2u(__half2 h){ union{ __half2 h; uint32_t u; } c; c.h = h; return c.u; }
__device__ __forceinline__ __half2 u2h(uint32_t u){ union{ uint32_t u; __half2 h; } c; c.u = u; return c.h; }

// swizzled LDS byte offset for GEMM tiles: [128 rows][8 chunks of 16B], chunk ^= row&7
__device__ __forceinline__ int sw(int r, int c) { return r * 128 + ((c ^ (r & 7)) << 4); }

__device__ __forceinline__ uint4 cvt8(float4 a, float4 b) {
    uint4 u;
    u.x = h2u(__floats2half2_rn(a.x, a.y));
    u.y = h2u(__floats2half2_rn(a.z, a.w));
    u.z = h2u(__floats2half2_rn(b.x, b.y));
    u.w = h2u(__floats2half2_rn(b.z, b.w));
    return u;
}

// ---------------------------------------------------------------------------
// MFMA GEMM: C[M x N](fp16) = act( A[M x K] @ W[N x K]^T + bias )
// 128x128 tile, BK=64, 4 waves (2x2), each wave 4x4 frags of 16x16x32_f16.
// Grid: x = nt (few), y = mt -- consecutive blocks share the A-tile.
// Epilogue: stage C in LDS, write 256B contiguous per row (r8 counters showed
// the old scattered 32B stores caused 4.7x write inflation: 235MB vs 50MB).
// ---------------------------------------------------------------------------
template<int KD, bool AF32, bool RELU>
__global__ __launch_bounds__(256, 2)
void mfma_gemm(const float* __restrict__ Af, const __half* __restrict__ Ah,
               const __half* __restrict__ Bh, const float* __restrict__ bias,
               uint32_t* __restrict__ C, int N)
{
    __shared__ __align__(16) __half smem[2 * 128 * 64];   // As | Bs; Cs in epilogue
    __half* As = smem;
    __half* Bs = smem + 128 * 64;
    const int m0 = blockIdx.y * 128, n0 = blockIdx.x * 128;
    const int tid = threadIdx.x;
    const int r = tid >> 1, cb = (tid & 1) * 4;
    const int lane = tid & 63, w = tid >> 6;
    const int wm = w >> 1, wn = w & 1;
    const int l15 = lane & 15, lq = lane >> 4;
    constexpr int KT = KD / 64;

    f32x4 acc[4][4];
    #pragma unroll
    for (int i = 0; i < 4; ++i)
        #pragma unroll
        for (int j = 0; j < 4; ++j) {
            f32x4 z = {0.f, 0.f, 0.f, 0.f};
            acc[i][j] = z;
        }

    uint4 sa[4], sb[4];
    float4 sa32[8];

    auto loads = [&](int kt) {
        if constexpr (AF32) {
            const float* ap = Af + (size_t)(m0 + r) * KD + kt * 64 + cb * 8;
            #pragma unroll
            for (int c = 0; c < 4; ++c) {
                sa32[2 * c]     = ((const float4*)ap)[2 * c];
                sa32[2 * c + 1] = ((const float4*)ap)[2 * c + 1];
            }
        } else {
            const __half* ap = Ah + (size_t)(m0 + r) * KD + kt * 64 + cb * 8;
            #pragma unroll
            for (int c = 0; c < 4; ++c) sa[c] = ((const uint4*)ap)[c];
        }
        const __half* bp = Bh + (size_t)(n0 + r) * KD + kt * 64 + cb * 8;
        #pragma unroll
        for (int c = 0; c < 4; ++c) sb[c] = ((const uint4*)bp)[c];
    };

    auto dswrite = [&]() {
        #pragma unroll
        for (int c = 0; c < 4; ++c) {
            uint4 va;
            if constexpr (AF32) va = cvt8(sa32[2 * c], sa32[2 * c + 1]);
            else                va = sa[c];
            *(uint4*)((char*)As + sw(r, cb + c)) = va;
            *(uint4*)((char*)Bs + sw(r, cb + c)) = sb[c];
        }
    };

    auto compute = [&]() {
        #pragma unroll
        for (int kc = 0; kc < 2; ++kc) {
            f16x8 af[4], bf[4];
            #pragma unroll
            for (int mi = 0; mi < 4; ++mi)
                af[mi] = *(const f16x8*)((const char*)As + sw(wm * 64 + mi * 16 + l15, kc * 4 + lq));
            #pragma unroll
            for (int ni = 0; ni < 4; ++ni)
                bf[ni] = *(const f16x8*)((const char*)Bs + sw(wn * 64 + ni * 16 + l15, kc * 4 + lq));
            #pragma unroll
            for (int mi = 0; mi < 4; ++mi)
                #pragma unroll
                for (int ni = 0; ni < 4; ++ni)
                    acc[mi][ni] = __builtin_amdgcn_mfma_f32_16x16x32_f16(af[mi], bf[ni], acc[mi][ni], 0, 0, 0);
        }
    };

    loads(0);
    for (int kt = 0; kt < KT; ++kt) {
        __syncthreads();
        dswrite();
        __syncthreads();
        if (kt + 1 < KT) loads(kt + 1);
        compute();
    }

    // ---- epilogue: stage to LDS, then fully-coalesced 256B row writes ----
    __syncthreads();                         // K-loop LDS reads done
    uint32_t* Cs = (uint32_t*)smem;          // [128][64] uint32 = 32KB
    #pragma unroll
    for (int ni = 0; ni < 4; ++ni) {
        const float bv = bias[n0 + wn * 64 + ni * 16 + l15];
        #pragma unroll
        for (int mi = 0; mi < 4; ++mi) {
            f32x4 d = acc[mi][ni];
            #pragma unroll
            for (int rr = 0; rr < 4; ++rr) {
                float v = d[rr] + bv;
                if (RELU) v = fmaxf(v, 0.0f);
                uint32_t u = (uint32_t)__half_as_ushort(__float2half(v));
                uint32_t nb = (uint32_t)__shfl_xor((int)u, 1);
                if (!(lane & 1))
                    Cs[(wm * 64 + mi * 16 + lq * 4 + rr) * 64 + wn * 32 + ni * 8 + (l15 >> 1)] = u | (nb << 16);
            }
        }
    }
    __syncthreads();
    const int orow = tid >> 4, ocol = (tid & 15) * 4;   // 16 thr x 16B per row
    #pragma unroll
    for (int gp = 0; gp < 8; ++gp) {
        const int row = gp * 16 + orow;
        const uint4 val = *(const uint4*)&Cs[row * 64 + ocol];
        *(uint4*)(C + (size_t)(m0 + row) * (N >> 1) + (n0 >> 1) + ocol) = val;
    }
}

// ---------------------------------------------------------------------------
// Weight packs. pack_whh zeroes qctl and splits W_hh into:
//   WhhR: per-thread regs, K-chunks 0..5 (36 uint4/thread, contiguous)
//   WhhL: frag-major [12][512] uint4, K-chunks 6..7 (block copies into LDS)
// (unchanged -- passed r8)
// ---------------------------------------------------------------------------
__global__ void pack_half(const float* __restrict__ in, uint32_t* __restrict__ out, int n2)
{
    int i = blockIdx.x * 256 + threadIdx.x;
    if (i < n2) {
        float2 f = ((const float2*)in)[i];
        out[i] = h2u(__floats2half2_rn(f.x, f.y));
    }
}

__global__ void pack_whh(const float* __restrict__ Whh, uint32_t* __restrict__ outR,
                         uint32_t* __restrict__ outL, int* __restrict__ qctl)
{
    if (blockIdx.x == 0 && threadIdx.x == 0) { qctl[0] = 0; qctl[1] = 0; }
    int p = blockIdx.x * 256 + threadIdx.x;
    if (p >= 512 * 192) return;
    const int v4 = p >> 2, sub = p & 3;
    const int t = v4 / 48, ic = v4 - t * 48;
    const int i = ic >> 3, c = ic & 7;
    const int w = t >> 6, lane = t & 63;
    const int row = w * 96 + i * 16 + (lane & 15);
    const int kb = c * 32 + ((lane >> 4) << 3) + sub * 2;
    const uint32_t val = h2u(__floats2half2_rn(Whh[row * 256 + kb], Whh[row * 256 + kb + 1]));
    if (c < 6) outR[(t * 36 + i * 6 + c) * 4 + sub] = val;
    else       outL[(((i << 1) + (c - 6)) * 512 + t) * 4 + sub] = val;
}

// ---------------------------------------------------------------------------
// Segment builder (unchanged -- passed r6/r8).
// ---------------------------------------------------------------------------
__global__ __launch_bounds__(512)
void seg_build(const int* __restrict__ masks, int* __restrict__ queue,
               int* __restrict__ qtail)
{
    __shared__ int sc[512];
    __shared__ int starts[512];
    __shared__ int cshr[2];
    const int b = blockIdx.x, s = threadIdx.x;
    const int is = (s == 0) || (masks[b * (T_ - 1) + s - 1] == 0);
    sc[s] = is;
    __syncthreads();
    #pragma unroll
    for (int off = 1; off < 512; off <<= 1) {
        int v = (s >= off) ? sc[s - off] : 0;
        __syncthreads();
        sc[s] += v;
        __syncthreads();
    }
    if (is) starts[sc[s] - 1] = s;
    if (s == 511) cshr[0] = sc[511];
    __syncthreads();
    const int cnt = cshr[0];
    int valid = 0, st = 0, ln = 0;
    if (s < cnt) {
        st = starts[s];
        const int nxt = (s + 1 < cnt) ? starts[s + 1] : T_;
        ln = nxt - st;
        valid = (st == 0 || ln >= 2) ? 1 : 0;
    }
    sc[s] = valid;
    __syncthreads();
    #pragma unroll
    for (int off = 1; off < 512; off <<= 1) {
        int v = (s >= off) ? sc[s - off] : 0;
        __syncthreads();
        sc[s] += v;
        __syncthreads();
    }
    if (s == 511) cshr[1] = atomicAdd(qtail, sc[511]);
    __syncthreads();
    if (valid) queue[cshr[1] + sc[s] - 1] = (b << 19) | (st << 10) | ln;
}

// ---------------------------------------------------------------------------
// Pre-pass, grid-stride (unchanged -- passed r8).
// ---------------------------------------------------------------------------
__global__ __launch_bounds__(256)
void h0pre(const __half* __restrict__ gx, const float* __restrict__ bhh,
           const int* __restrict__ masks, uint32_t* __restrict__ hs2)
{
    for (int row = blockIdx.x; row < B_ * (T_ - 1); row += gridDim.x) {
        if (masks[row] != 0) continue;
        const int b = row / (T_ - 1), t = 1 + row - b * (T_ - 1);
        const int e = threadIdx.x;
        const __half* grow = gx + (size_t)(b * T_ + t) * 768;
        const float gxr = __half2float(grow[e]);
        const float gxz = __half2float(grow[e + 256]);
        const float gxn = __half2float(grow[e + 512]);
        const float rg = 1.f / (1.f + exp2f(-(gxr + bhh[e]) * 1.44269504f));
        const float zg = 1.f / (1.f + exp2f(-(gxz + bhh[e + 256]) * 1.44269504f));
        const float nin = gxn + rg * bhh[e + 512];
        const float e2x = exp2f(nin * 2.885390082f);
        const float ng = 1.f - 2.f / (e2x + 1.f);
        const float hnew = (1.f - zg) * ng;     // h_prev = 0
        const float other = __shfl_xor(hnew, 1);
        if (!(e & 1)) hs2[(size_t)(b * T_ + t) * 128 + (e >> 1)] = h2u(__floats2half2_rn(hnew, other));
    }
}

// ---------------------------------------------------------------------------
// MFMA slot-parallel GRU v3 (unchanged -- passed r8, dropped out of top-5).
// ---------------------------------------------------------------------------
__global__ __launch_bounds__(512, 2)
void gru_mfma(const __half* __restrict__ gx, const uint4* __restrict__ WhhR,
              const uint4* __restrict__ WhhL, const float* __restrict__ bhh,
              const float* __restrict__ h0, const int* __restrict__ queue,
              const int* __restrict__ qctl, uint32_t* __restrict__ hs2)
{
    __shared__ __align__(16) __half Hl[NSLOT * 256];   // 8KB, granule-swizzled
    __shared__ __align__(16) __half Plh[NSLOT * 784];  // 24.5KB gh (fp16)
    __shared__ __align__(16) uint4  Wl[12 * 512];      // 98KB W_hh K-chunks 6..7
    __shared__ float Bl[G_];
    __shared__ int s_end[NSLOT], s_row[NSLOT], s_act[NSLOT], s_nxt[NSLOT];
    __shared__ int cur;

    const int tid = threadIdx.x;
    const int lane = tid & 63, w = tid >> 6;
    const int s = tid >> 5, g32 = tid & 31, e0 = g32 * 8;
    const int col = lane & 15, lq = lane >> 4;

    f16x8 wr[36];
    {
        const f16x8* wp = (const f16x8*)(WhhR + (size_t)tid * 36);
        #pragma unroll
        for (int i = 0; i < 36; ++i) wr[i] = wp[i];
    }
    #pragma unroll
    for (int i = 0; i < 12; ++i) Wl[i * 512 + tid] = WhhL[i * 512 + tid];
    if (tid < 384) { Bl[tid] = bhh[tid]; Bl[tid + 384] = bhh[tid + 384]; }
    { const uint4 z4 = {0u, 0u, 0u, 0u}; *(uint4*)((char*)Hl + tid * 16) = z4; }

    const int NQ = qctl[0];
    const int gb = blockIdx.x;
    const int lo = (int)(((long long)NQ * gb) >> 8);
    const int hi = (int)(((long long)NQ * (gb + 1)) >> 8);
    if (tid == 0) cur = lo + NSLOT;
    __syncthreads();

    {
        int e = -1;
        if (lo + s < hi) e = queue[lo + s];
        if (e >= 0) {
            const int ln = e & 1023, st = (e >> 10) & 511, nb = e >> 19;
            uint4 hseed;
            if (st == 0) {
                const float4 a = *(const float4*)(h0 + nb * 256 + e0);
                const float4 b = *(const float4*)(h0 + nb * 256 + e0 + 4);
                hseed = cvt8(a, b);
                if (g32 == 0) { s_row[s] = nb * T_; s_end[s] = nb * T_ + ln; }
            } else {
                hseed = *(const uint4*)(hs2 + (size_t)(nb * T_ + st) * 128 + g32 * 4);
                if (g32 == 0) { s_row[s] = nb * T_ + st + 1; s_end[s] = nb * T_ + st + ln; }
            }
            *(uint4*)((char*)Hl + s * 512 + ((g32 ^ (s & 7)) << 4)) = hseed;
            if (g32 == 0) {
                s_act[s] = 1;
                const int p = atomicAdd(&cur, 1);
                s_nxt[s] = (p < hi) ? queue[p] : -1;
            }
        } else if (g32 == 0) {
            s_act[s] = 0; s_nxt[s] = -1; s_row[s] = 0; s_end[s] = 0;
        }
    }
    __syncthreads();

    for (;;) {
        bool alive = false;
        #pragma unroll
        for (int i = 0; i < NSLOT; ++i) alive |= (s_act[i] != 0);
        if (!alive) break;

        // ---- phase X ----
        const int myrow = s_row[s];
        const int nxte = s_nxt[s];
        const __half* grow = gx + (size_t)myrow * G_;
        const f16x8 gr = *(const f16x8*)(grow + e0);
        const f16x8 gz = *(const f16x8*)(grow + 256 + e0);
        const f16x8 gn = *(const f16x8*)(grow + 512 + e0);
        uint4 su = {0u, 0u, 0u, 0u};
        if (nxte >= 0) {
            const int st = (nxte >> 10) & 511, nb = nxte >> 19;
            if (st == 0) {
                const float4 a = *(const float4*)(h0 + nb * 256 + e0);
                const float4 b = *(const float4*)(h0 + nb * 256 + e0 + 4);
                su = cvt8(a, b);
            } else {
                su = *(const uint4*)(hs2 + (size_t)(nb * T_ + st) * 128 + g32 * 4);
            }
        }
        f16x8 bfv[8];
        #pragma unroll
        for (int c = 0; c < 8; ++c)
            bfv[c] = *(const f16x8*)((const char*)Hl + col * 512 +
                                     ((((c << 2) + lq) ^ (col & 7)) << 4));
        f32x4 acc[6];
        #pragma unroll
        for (int i = 0; i < 6; ++i) { const f32x4 z = {0.f, 0.f, 0.f, 0.f}; acc[i] = z; }
        #pragma unroll
        for (int c = 0; c < 6; ++c)
            #pragma unroll
            for (int i = 0; i < 6; ++i)
                acc[i] = __builtin_amdgcn_mfma_f32_16x16x32_f16(wr[i * 6 + c], bfv[c], acc[i], 0, 0, 0);
        #pragma unroll
        for (int c2 = 0; c2 < 2; ++c2)
            #pragma unroll
            for (int i = 0; i < 6; ++i) {
                const f16x8 wlt = *(const f16x8*)&Wl[(i * 2 + c2) * 512 + tid];
                acc[i] = __builtin_amdgcn_mfma_f32_16x16x32_f16(wlt, bfv[6 + c2], acc[i], 0, 0, 0);
            }
        #pragma unroll
        for (int i = 0; i < 6; ++i) {
            uint2 ph;
            ph.x = h2u(__floats2half2_rn(acc[i][0], acc[i][1]));
            ph.y = h2u(__floats2half2_rn(acc[i][2], acc[i][3]));
            *(uint2*)(Plh + col * 784 + (w * 96 + i * 16 + lq * 4)) = ph;
        }
        asm volatile("s_waitcnt lgkmcnt(0)" ::: "memory");
        __builtin_amdgcn_s_barrier();

        // ---- phase Y ----
        if (s_act[s]) {
            const __half* Pr = Plh + s * 784;
            const f16x8 R  = *(const f16x8*)(Pr + e0);
            const f16x8 Z  = *(const f16x8*)(Pr + 256 + e0);
            const f16x8 Nn = *(const f16x8*)(Pr + 512 + e0);
            const f32x4 br0 = *(const f32x4*)(Bl + e0),       br1 = *(const f32x4*)(Bl + e0 + 4);
            const f32x4 bz0 = *(const f32x4*)(Bl + 256 + e0), bz1 = *(const f32x4*)(Bl + 256 + e0 + 4);
            const f32x4 bn0 = *(const f32x4*)(Bl + 512 + e0), bn1 = *(const f32x4*)(Bl + 512 + e0 + 4);
            const uint4 hp4 = *(const uint4*)((const char*)Hl + s * 512 + ((g32 ^ (s & 7)) << 4));
            const __half2 q0 = u2h(hp4.x), q1 = u2h(hp4.y), q2 = u2h(hp4.z), q3 = u2h(hp4.w);
            const float hpv[8] = { __low2float(q0), __high2float(q0), __low2float(q1), __high2float(q1),
                                   __low2float(q2), __high2float(q2), __low2float(q3), __high2float(q3) };
            float hn[8];
            #pragma unroll
            for (int j = 0; j < 8; ++j) {
                const float ghr = (float)R[j]  + (j < 4 ? br0[j] : br1[j - 4]);
                const float ghz = (float)Z[j]  + (j < 4 ? bz0[j] : bz1[j - 4]);
                const float ghn = (float)Nn[j] + (j < 4 ? bn0[j] : bn1[j - 4]);
                const float rg = 1.f / (1.f + exp2f(-((float)gr[j] + ghr) * 1.44269504f));
                const float zg = 1.f / (1.f + exp2f(-((float)gz[j] + ghz) * 1.44269504f));
                const float nin = (float)gn[j] + rg * ghn;
                const float ex = exp2f(nin * 2.885390082f);
                const float ng = 1.f - 2.f / (ex + 1.f);
                hn[j] = (1.f - zg) * ng + zg * hpv[j];
            }
            uint4 hp;
            hp.x = h2u(__floats2half2_rn(hn[0], hn[1]));
            hp.y = h2u(__floats2half2_rn(hn[2], hn[3]));
            hp.z = h2u(__floats2half2_rn(hn[4], hn[5]));
            hp.w = h2u(__floats2half2_rn(hn[6], hn[7]));
            *(uint4*)(hs2 + (size_t)myrow * 128 + g32 * 4) = hp;
            if (myrow + 1 < s_end[s]) {
                *(uint4*)((char*)Hl + s * 512 + ((g32 ^ (s & 7)) << 4)) = hp;
                if (g32 == 0) s_row[s] = myrow + 1;
            } else if (nxte >= 0) {
                const int ln = nxte & 1023, st = (nxte >> 10) & 511, nb = nxte >> 19;
                *(uint4*)((char*)Hl + s * 512 + ((g32 ^ (s & 7)) << 4)) = su;
                if (g32 == 0) {
                    if (st == 0) { s_row[s] = nb * T_;          s_end[s] = nb * T_ + ln; }
                    else         { s_row[s] = nb * T_ + st + 1; s_end[s] = nb * T_ + st + ln; }
                    const int p = atomicAdd(&cur, 1);
                    s_nxt[s] = (p < hi) ? queue[p] : -1;
                }
            } else if (g32 == 0) {
                s_act[s] = 0;
            }
        }
        asm volatile("s_waitcnt lgkmcnt(0)" ::: "memory");
        __builtin_amdgcn_s_barrier();
    }
}

// ---------------------------------------------------------------------------
// Heads (unchanged, passed): one wave per output row, hs fp16.
// ---------------------------------------------------------------------------
__global__ __launch_bounds__(256)
void heads_kernel(const uint32_t* __restrict__ hs2, const float* __restrict__ Wa,
                  const float* __restrict__ ba, const float* __restrict__ Wc,
                  const float* __restrict__ bc, const int* __restrict__ action,
                  float* __restrict__ out)
{
    const int wid = threadIdx.x >> 6, lane = threadIdx.x & 63;
    const int row = blockIdx.x * 4 + wid;
    const uint2 hv2 = ((const uint2*)(hs2 + (size_t)row * 128))[lane];
    const __half2 ha = u2h(hv2.x), hb = u2h(hv2.y);
    const float h0f = __low2float(ha), h1f = __high2float(ha);
    const float h2f = __low2float(hb), h3f = __high2float(hb);
    float sums[11];
    #pragma unroll
    for (int n = 0; n < 11; ++n) {
        const float* wrow = (n < 10) ? (Wa + n * 256) : Wc;
        const float4 wv = ((const float4*)wrow)[lane];
        sums[n] = h0f * wv.x + h1f * wv.y + h2f * wv.z + h3f * wv.w;
    }
    #pragma unroll
    for (int n = 0; n < 11; ++n) {
        float v = sums[n];
        #pragma unroll
        for (int off = 32; off; off >>= 1) v += __shfl_xor(v, off);
        sums[n] = v;
    }
    float logits[10];
    #pragma unroll
    for (int n = 0; n < 10; ++n) logits[n] = sums[n] + ba[n];
    const float value = sums[10] + bc[0];
    float mx = logits[0];
    #pragma unroll
    for (int n = 1; n < 10; ++n) mx = fmaxf(mx, logits[n]);
    float ssum = 0.f, sdot = 0.f;
    #pragma unroll
    for (int n = 0; n < 10; ++n) {
        float d = logits[n] - mx;
        float e = exp2f(d * 1.44269504f);
        ssum += e; sdot += e * d;
    }
    const float lns = logf(ssum);
    const float lse = mx + lns;
    const float entropy = lns - sdot / ssum;
    const int a = action[row];
    float la = 0.f;
    #pragma unroll
    for (int n = 0; n < 10; ++n) la = (n == a) ? logits[n] : la;
    if (lane == 0) {
        out[row] = value;
        out[BT_ + row] = la - lse;
        out[2 * BT_ + row] = entropy;
    }
}

// ---------------------------------------------------------------------------
extern "C" void kernel_launch(void* const* d_in, const int* in_sizes, int n_in,
                              void* d_out, int out_size, void* d_ws, size_t ws_size,
                              hipStream_t stream)
{
    const float* obs    = (const float*)d_in[0];
    const int*   action = (const int*)d_in[1];
    const int*   masks  = (const int*)d_in[2];
    const float* h0     = (const float*)d_in[3];
    const float* W1     = (const float*)d_in[4];
    const float* b1     = (const float*)d_in[5];
    const float* Wih    = (const float*)d_in[6];
    const float* Whh    = (const float*)d_in[7];
    const float* bih    = (const float*)d_in[8];
    const float* bhh    = (const float*)d_in[9];
    const float* Wa     = (const float*)d_in[10];
    const float* ba     = (const float*)d_in[11];
    const float* Wc     = (const float*)d_in[12];
    const float* bc     = (const float*)d_in[13];
    float* out = (float*)d_out;

    char* p = (char*)d_ws;
    __half*   feat = (__half*)p;    p += (size_t)BT_ * FEAT_ * 2;   // 33.6 MB
    __half*   gx   = (__half*)p;    p += (size_t)BT_ * G_ * 2;      // 50.3 MB
    uint32_t* hs2  = (uint32_t*)p;  p += (size_t)BT_ * H_ * 2;      // 16.8 MB
    uint32_t* W1h  = (uint32_t*)p;  p += FEAT_ * OBS_ * 2;          // 131 KB
    uint32_t* Wihh = (uint32_t*)p;  p += G_ * FEAT_ * 2;            // 786 KB
    uint4*    WhhR = (uint4*)p;     p += 512 * 36 * 16;             // 295 KB
    uint4*    WhhL = (uint4*)p;     p += 12 * 512 * 16;             // 98 KB
    int*      queue= (int*)p;       p += B_ * 512 * 4;              // 131 KB
    int*      qctl = (int*)p;       p += 256;                       // [0]=tail

    // packs (pack_whh zeroes qctl) + segment queue build
    pack_half<<<(FEAT_ * OBS_ / 2 + 255) / 256, 256, 0, stream>>>(W1, W1h, FEAT_ * OBS_ / 2);
    pack_half<<<(G_ * FEAT_ / 2 + 255) / 256, 256, 0, stream>>>(Wih, Wihh, G_ * FEAT_ / 2);
    pack_whh<<<384, 256, 0, stream>>>(Whh, (uint32_t*)WhhR, (uint32_t*)WhhL, qctl);
    seg_build<<<B_, 512, 0, stream>>>(masks, queue, &qctl[0]);
    // feat = relu(obs @ W1^T + b1)   (grid: x=nt so A-tile-sharing blocks adjacent)
    mfma_gemm<OBS_, true, true><<<dim3(4, 256), 256, 0, stream>>>(obs, nullptr, (const __half*)W1h, b1, (uint32_t*)feat, FEAT_);
    // gx = feat @ W_ih^T + b_ih   (batch-major rows)
    mfma_gemm<FEAT_, false, false><<<dim3(6, 256), 256, 0, stream>>>(nullptr, feat, (const __half*)Wihh, bih, (uint32_t*)gx, G_);
    // pre-pass: all h_prev==0 steps (elementwise, grid-stride)
    h0pre<<<2048, 256, 0, stream>>>(gx, bhh, masks, hs2);
    // MFMA slot-parallel recurrence (static slices, 2 barriers/iter, pre-pop)
    gru_mfma<<<256, 512, 0, stream>>>(gx, WhhR, WhhL, bhh, h0, queue, qctl, hs2);
    // heads
    heads_kernel<<<8192, 256, 0, stream>>>(hs2, Wa, ba, Wc, bc, action, out);
}

// Round 10
// 225.656 us; speedup vs baseline: 1.3410x; 1.0043x over previous
//
#include <hip/hip_runtime.h>
#include <hip/hip_fp16.h>
#include <stdint.h>

#define B_    64
#define T_    512
#define OBS_  128
#define FEAT_ 512
#define H_    256
#define G_    768
#define BT_   32768
#define NSLOT 16

typedef _Float16 f16x8 __attribute__((ext_vector_type(8)));
typedef float    f32x4 __attribute__((ext_vector_type(4)));

__device__ __forceinline__ uint32_t h2u(__half2 h){ union{ __half2 h; uint32_t u; } c; c.h = h; return c.u; }
__device__ __forceinline__ __half2 u2h(uint32_t u){ union{ uint32_t u; __half2 h; } c; c.u = u; return c.h; }

// swizzled LDS byte offset: [rows][8 chunks of 16B], chunk ^= row&7
__device__ __forceinline__ int sw(int r, int c) { return r * 128 + ((c ^ (r & 7)) << 4); }

__device__ __forceinline__ uint4 cvt8(float4 a, float4 b) {
    uint4 u;
    u.x = h2u(__floats2half2_rn(a.x, a.y));
    u.y = h2u(__floats2half2_rn(a.z, a.w));
    u.z = h2u(__floats2half2_rn(b.x, b.y));
    u.w = h2u(__floats2half2_rn(b.z, b.w));
    return u;
}

// ---------------------------------------------------------------------------
// Fused feat+gx GEMM. One block = 128 rows (m-tile) x 256 gx-cols (n-slice).
// Grid 768 = 256 m x 3 n, id: m = bid&255, n = bid>>8 -> the 3 blocks sharing
// an obs tile land on the SAME XCD (256 % 8 == 0). Per j in 0..3:
//   stage W1 rows j*128.. -> feat_sub[128x128] = relu(obs@W1^T+b1) -> featL
//   (LDS, panel-swizzled), then gx_acc += feat_sub @ Wih^T over two BK=64.
// feat (33.6MB) never touches HBM -- r9 showed both its write and re-read
// arrive ~3.5x amplified. Epilogue: Cs-staged, 512B-contiguous row stores.
// ---------------------------------------------------------------------------
__global__ __launch_bounds__(512, 2)
void fused_gemm(const float* __restrict__ obs, const __half* __restrict__ W1h,
                const __half* __restrict__ Wihh, const float* __restrict__ b1,
                const float* __restrict__ bih, uint32_t* __restrict__ gxC)
{
    __shared__ __align__(16) __half smem[49152];   // 96KB: obsA 32 | featL 32 | Bs 32
    __half* obsA  = smem;            // [2 panels of 16KB][128r][64h] swizzled
    __half* featL = smem + 16384;    // same layout
    __half* BsS   = smem + 32768;    // stage1: 128x64; stage2: 256x64

    const int bid = blockIdx.x;
    const int m0 = (bid & 255) * 128;
    const int n0 = (bid >> 8) * 256;
    const int tid = threadIdx.x;
    const int lane = tid & 63, w = tid >> 6;
    const int wm = w >> 2, wn = w & 3;     // 2x4 waves
    const int l15 = lane & 15, lq = lane >> 4;

    // ---- stage obs tile once (fp32 -> fp16, both K-panels) ----
    {
        const int r = tid >> 2, c0 = (tid & 3) * 4;
        const float* ap = obs + (size_t)(m0 + r) * OBS_ + c0 * 8;
        #pragma unroll
        for (int c = 0; c < 4; ++c) {
            const float4 f0 = ((const float4*)ap)[c * 2];
            const float4 f1 = ((const float4*)ap)[c * 2 + 1];
            const int cc = c0 + c;
            *(uint4*)((char*)obsA + (cc >> 3) * 16384 + sw(r, cc & 7)) = cvt8(f0, f1);
        }
    }

    f32x4 acc2[4][4];
    #pragma unroll
    for (int i = 0; i < 4; ++i)
        #pragma unroll
        for (int jj = 0; jj < 4; ++jj) { const f32x4 z = {0.f,0.f,0.f,0.f}; acc2[i][jj] = z; }

    for (int j = 0; j < 4; ++j) {
        // ---- stage 1: feat_sub[128x128] = relu(obs @ W1^T + b1), K=128 ----
        f32x4 acc1[4][2];
        #pragma unroll
        for (int i = 0; i < 4; ++i)
            #pragma unroll
            for (int jj = 0; jj < 2; ++jj) { const f32x4 z = {0.f,0.f,0.f,0.f}; acc1[i][jj] = z; }
        #pragma unroll
        for (int kt = 0; kt < 2; ++kt) {
            __syncthreads();                       // Bs free (prev compute done)
            if (tid < 256) {                       // stage W1 tile 128x64
                const int r = tid >> 1, cb = (tid & 1) * 4;
                const __half* bp = W1h + (size_t)(j * 128 + r) * OBS_ + kt * 64 + cb * 8;
                #pragma unroll
                for (int c = 0; c < 4; ++c)
                    *(uint4*)((char*)BsS + sw(r, cb + c)) = ((const uint4*)bp)[c];
            }
            __syncthreads();
            #pragma unroll
            for (int kc = 0; kc < 2; ++kc) {
                f16x8 af[4], bf[2];
                #pragma unroll
                for (int mi = 0; mi < 4; ++mi)
                    af[mi] = *(const f16x8*)((const char*)obsA + kt * 16384 +
                                             sw(wm * 64 + mi * 16 + l15, kc * 4 + lq));
                #pragma unroll
                for (int ni = 0; ni < 2; ++ni)
                    bf[ni] = *(const f16x8*)((const char*)BsS +
                                             sw(wn * 32 + ni * 16 + l15, kc * 4 + lq));
                #pragma unroll
                for (int mi = 0; mi < 4; ++mi)
                    #pragma unroll
                    for (int ni = 0; ni < 2; ++ni)
                        acc1[mi][ni] = __builtin_amdgcn_mfma_f32_16x16x32_f16(af[mi], bf[ni], acc1[mi][ni], 0, 0, 0);
            }
        }
        // ---- feat_sub -> featL (bias+relu, fp16, panel-swizzled) ----
        // write addr must equal stage-2 read addr: panel = col>>6,
        // chunk = (col>>3)&7, byte-in-chunk = (col&7)*2.
        #pragma unroll
        for (int ni = 0; ni < 2; ++ni) {
            const int col = wn * 32 + ni * 16 + l15;
            const float bv = b1[j * 128 + col];
            #pragma unroll
            for (int mi = 0; mi < 4; ++mi) {
                const f32x4 d = acc1[mi][ni];
                #pragma unroll
                for (int rr = 0; rr < 4; ++rr) {
                    const float v = fmaxf(d[rr] + bv, 0.0f);
                    const uint32_t u = (uint32_t)__half_as_ushort(__float2half(v));
                    const uint32_t nb = (uint32_t)__shfl_xor((int)u, 1);
                    if (!(lane & 1)) {
                        const int row = wm * 64 + mi * 16 + lq * 4 + rr;
                        *(uint32_t*)((char*)featL + (col >> 6) * 16384 + row * 128 +
                                     ((((col >> 3) & 7) ^ (row & 7)) << 4) + (col & 7) * 2) = u | (nb << 16);
                    }
                }
            }
        }
        // ---- stage 2: gx_acc += feat_sub @ Wih^T (two BK=64 chunks) ----
        #pragma unroll
        for (int kt2 = 0; kt2 < 2; ++kt2) {
            __syncthreads();                       // featL visible; Bs free
            {                                      // stage Wih tile 256x64
                const int r = tid >> 1, cb = (tid & 1) * 4;
                const __half* bp = Wihh + (size_t)(n0 + r) * FEAT_ + j * 128 + kt2 * 64 + cb * 8;
                #pragma unroll
                for (int c = 0; c < 4; ++c)
                    *(uint4*)((char*)BsS + sw(r, cb + c)) = ((const uint4*)bp)[c];
            }
            __syncthreads();
            #pragma unroll
            for (int kc = 0; kc < 2; ++kc) {
                f16x8 af[4], bf[4];
                #pragma unroll
                for (int mi = 0; mi < 4; ++mi)
                    af[mi] = *(const f16x8*)((const char*)featL + kt2 * 16384 +
                                             sw(wm * 64 + mi * 16 + l15, kc * 4 + lq));
                #pragma unroll
                for (int ni = 0; ni < 4; ++ni)
                    bf[ni] = *(const f16x8*)((const char*)BsS +
                                             sw(wn * 64 + ni * 16 + l15, kc * 4 + lq));
                #pragma unroll
                for (int mi = 0; mi < 4; ++mi)
                    #pragma unroll
                    for (int ni = 0; ni < 4; ++ni)
                        acc2[mi][ni] = __builtin_amdgcn_mfma_f32_16x16x32_f16(af[mi], bf[ni], acc2[mi][ni], 0, 0, 0);
            }
        }
    }

    // ---- epilogue: Cs staging (reuses obsA+featL), 512B-contiguous rows ----
    __syncthreads();
    uint32_t* Cs = (uint32_t*)smem;                // [128][128] uint32 = 64KB
    #pragma unroll
    for (int ni = 0; ni < 4; ++ni) {
        const int col = wn * 64 + ni * 16 + l15;
        const float bv = bih[n0 + col];
        #pragma unroll
        for (int mi = 0; mi < 4; ++mi) {
            const f32x4 d = acc2[mi][ni];
            #pragma unroll
            for (int rr = 0; rr < 4; ++rr) {
                const float v = d[rr] + bv;
                const uint32_t u = (uint32_t)__half_as_ushort(__float2half(v));
                const uint32_t nb = (uint32_t)__shfl_xor((int)u, 1);
                if (!(lane & 1))
                    Cs[(wm * 64 + mi * 16 + lq * 4 + rr) * 128 + (col >> 1)] = u | (nb << 16);
            }
        }
    }
    __syncthreads();
    const int orow = tid >> 2, oq = (tid & 3) * 32;    // 4 thr x 128B per row
    #pragma unroll
    for (int c = 0; c < 8; ++c) {
        const uint4 val = *(const uint4*)&Cs[orow * 128 + oq + c * 4];
        *(uint4*)(gxC + (size_t)(m0 + orow) * (G_ / 2) + (n0 >> 1) + oq + c * 4) = val;
    }
}

// ---------------------------------------------------------------------------
// Weight packs (unchanged -- passed r8/r9). pack_whh zeroes qctl and splits
// W_hh into WhhR (reg K-chunks 0..5) + WhhL (LDS K-chunks 6..7, frag-major).
// ---------------------------------------------------------------------------
__global__ void pack_half(const float* __restrict__ in, uint32_t* __restrict__ out, int n2)
{
    int i = blockIdx.x * 256 + threadIdx.x;
    if (i < n2) {
        float2 f = ((const float2*)in)[i];
        out[i] = h2u(__floats2half2_rn(f.x, f.y));
    }
}

__global__ void pack_whh(const float* __restrict__ Whh, uint32_t* __restrict__ outR,
                         uint32_t* __restrict__ outL, int* __restrict__ qctl)
{
    if (blockIdx.x == 0 && threadIdx.x == 0) { qctl[0] = 0; qctl[1] = 0; }
    int p = blockIdx.x * 256 + threadIdx.x;
    if (p >= 512 * 192) return;
    const int v4 = p >> 2, sub = p & 3;
    const int t = v4 / 48, ic = v4 - t * 48;
    const int i = ic >> 3, c = ic & 7;
    const int w = t >> 6, lane = t & 63;
    const int row = w * 96 + i * 16 + (lane & 15);
    const int kb = c * 32 + ((lane >> 4) << 3) + sub * 2;
    const uint32_t val = h2u(__floats2half2_rn(Whh[row * 256 + kb], Whh[row * 256 + kb + 1]));
    if (c < 6) outR[(t * 36 + i * 6 + c) * 4 + sub] = val;
    else       outL[(((i << 1) + (c - 6)) * 512 + t) * 4 + sub] = val;
}

// ---------------------------------------------------------------------------
// Segment builder (unchanged -- passed r6/r8/r9).
// ---------------------------------------------------------------------------
__global__ __launch_bounds__(512)
void seg_build(const int* __restrict__ masks, int* __restrict__ queue,
               int* __restrict__ qtail)
{
    __shared__ int sc[512];
    __shared__ int starts[512];
    __shared__ int cshr[2];
    const int b = blockIdx.x, s = threadIdx.x;
    const int is = (s == 0) || (masks[b * (T_ - 1) + s - 1] == 0);
    sc[s] = is;
    __syncthreads();
    #pragma unroll
    for (int off = 1; off < 512; off <<= 1) {
        int v = (s >= off) ? sc[s - off] : 0;
        __syncthreads();
        sc[s] += v;
        __syncthreads();
    }
    if (is) starts[sc[s] - 1] = s;
    if (s == 511) cshr[0] = sc[511];
    __syncthreads();
    const int cnt = cshr[0];
    int valid = 0, st = 0, ln = 0;
    if (s < cnt) {
        st = starts[s];
        const int nxt = (s + 1 < cnt) ? starts[s + 1] : T_;
        ln = nxt - st;
        valid = (st == 0 || ln >= 2) ? 1 : 0;
    }
    sc[s] = valid;
    __syncthreads();
    #pragma unroll
    for (int off = 1; off < 512; off <<= 1) {
        int v = (s >= off) ? sc[s - off] : 0;
        __syncthreads();
        sc[s] += v;
        __syncthreads();
    }
    if (s == 511) cshr[1] = atomicAdd(qtail, sc[511]);
    __syncthreads();
    if (valid) queue[cshr[1] + sc[s] - 1] = (b << 19) | (st << 10) | ln;
}

// ---------------------------------------------------------------------------
// Pre-pass, grid-stride (unchanged -- passed r8/r9).
// ---------------------------------------------------------------------------
__global__ __launch_bounds__(256)
void h0pre(const __half* __restrict__ gx, const float* __restrict__ bhh,
           const int* __restrict__ masks, uint32_t* __restrict__ hs2)
{
    for (int row = blockIdx.x; row < B_ * (T_ - 1); row += gridDim.x) {
        if (masks[row] != 0) continue;
        const int b = row / (T_ - 1), t = 1 + row - b * (T_ - 1);
        const int e = threadIdx.x;
        const __half* grow = gx + (size_t)(b * T_ + t) * 768;
        const float gxr = __half2float(grow[e]);
        const float gxz = __half2float(grow[e + 256]);
        const float gxn = __half2float(grow[e + 512]);
        const float rg = 1.f / (1.f + exp2f(-(gxr + bhh[e]) * 1.44269504f));
        const float zg = 1.f / (1.f + exp2f(-(gxz + bhh[e + 256]) * 1.44269504f));
        const float nin = gxn + rg * bhh[e + 512];
        const float e2x = exp2f(nin * 2.885390082f);
        const float ng = 1.f - 2.f / (e2x + 1.f);
        const float hnew = (1.f - zg) * ng;     // h_prev = 0
        const float other = __shfl_xor(hnew, 1);
        if (!(e & 1)) hs2[(size_t)(b * T_ + t) * 128 + (e >> 1)] = h2u(__floats2half2_rn(hnew, other));
    }
}

// ---------------------------------------------------------------------------
// MFMA slot-parallel GRU v3 (unchanged -- passed r8/r9).
// ---------------------------------------------------------------------------
__global__ __launch_bounds__(512, 2)
void gru_mfma(const __half* __restrict__ gx, const uint4* __restrict__ WhhR,
              const uint4* __restrict__ WhhL, const float* __restrict__ bhh,
              const float* __restrict__ h0, const int* __restrict__ queue,
              const int* __restrict__ qctl, uint32_t* __restrict__ hs2)
{
    __shared__ __align__(16) __half Hl[NSLOT * 256];   // 8KB, granule-swizzled
    __shared__ __align__(16) __half Plh[NSLOT * 784];  // 24.5KB gh (fp16)
    __shared__ __align__(16) uint4  Wl[12 * 512];      // 98KB W_hh K-chunks 6..7
    __shared__ float Bl[G_];
    __shared__ int s_end[NSLOT], s_row[NSLOT], s_act[NSLOT], s_nxt[NSLOT];
    __shared__ int cur;

    const int tid = threadIdx.x;
    const int lane = tid & 63, w = tid >> 6;
    const int s = tid >> 5, g32 = tid & 31, e0 = g32 * 8;
    const int col = lane & 15, lq = lane >> 4;

    f16x8 wr[36];
    {
        const f16x8* wp = (const f16x8*)(WhhR + (size_t)tid * 36);
        #pragma unroll
        for (int i = 0; i < 36; ++i) wr[i] = wp[i];
    }
    #pragma unroll
    for (int i = 0; i < 12; ++i) Wl[i * 512 + tid] = WhhL[i * 512 + tid];
    if (tid < 384) { Bl[tid] = bhh[tid]; Bl[tid + 384] = bhh[tid + 384]; }
    { const uint4 z4 = {0u, 0u, 0u, 0u}; *(uint4*)((char*)Hl + tid * 16) = z4; }

    const int NQ = qctl[0];
    const int gb = blockIdx.x;
    const int lo = (int)(((long long)NQ * gb) >> 8);
    const int hi = (int)(((long long)NQ * (gb + 1)) >> 8);
    if (tid == 0) cur = lo + NSLOT;
    __syncthreads();

    {
        int e = -1;
        if (lo + s < hi) e = queue[lo + s];
        if (e >= 0) {
            const int ln = e & 1023, st = (e >> 10) & 511, nb = e >> 19;
            uint4 hseed;
            if (st == 0) {
                const float4 a = *(const float4*)(h0 + nb * 256 + e0);
                const float4 b = *(const float4*)(h0 + nb * 256 + e0 + 4);
                hseed = cvt8(a, b);
                if (g32 == 0) { s_row[s] = nb * T_; s_end[s] = nb * T_ + ln; }
            } else {
                hseed = *(const uint4*)(hs2 + (size_t)(nb * T_ + st) * 128 + g32 * 4);
                if (g32 == 0) { s_row[s] = nb * T_ + st + 1; s_end[s] = nb * T_ + st + ln; }
            }
            *(uint4*)((char*)Hl + s * 512 + ((g32 ^ (s & 7)) << 4)) = hseed;
            if (g32 == 0) {
                s_act[s] = 1;
                const int p = atomicAdd(&cur, 1);
                s_nxt[s] = (p < hi) ? queue[p] : -1;
            }
        } else if (g32 == 0) {
            s_act[s] = 0; s_nxt[s] = -1; s_row[s] = 0; s_end[s] = 0;
        }
    }
    __syncthreads();

    for (;;) {
        bool alive = false;
        #pragma unroll
        for (int i = 0; i < NSLOT; ++i) alive |= (s_act[i] != 0);
        if (!alive) break;

        // ---- phase X ----
        const int myrow = s_row[s];
        const int nxte = s_nxt[s];
        const __half* grow = gx + (size_t)myrow * G_;
        const f16x8 gr = *(const f16x8*)(grow + e0);
        const f16x8 gz = *(const f16x8*)(grow + 256 + e0);
        const f16x8 gn = *(const f16x8*)(grow + 512 + e0);
        uint4 su = {0u, 0u, 0u, 0u};
        if (nxte >= 0) {
            const int st = (nxte >> 10) & 511, nb = nxte >> 19;
            if (st == 0) {
                const float4 a = *(const float4*)(h0 + nb * 256 + e0);
                const float4 b = *(const float4*)(h0 + nb * 256 + e0 + 4);
                su = cvt8(a, b);
            } else {
                su = *(const uint4*)(hs2 + (size_t)(nb * T_ + st) * 128 + g32 * 4);
            }
        }
        f16x8 bfv[8];
        #pragma unroll
        for (int c = 0; c < 8; ++c)
            bfv[c] = *(const f16x8*)((const char*)Hl + col * 512 +
                                     ((((c << 2) + lq) ^ (col & 7)) << 4));
        f32x4 acc[6];
        #pragma unroll
        for (int i = 0; i < 6; ++i) { const f32x4 z = {0.f, 0.f, 0.f, 0.f}; acc[i] = z; }
        #pragma unroll
        for (int c = 0; c < 6; ++c)
            #pragma unroll
            for (int i = 0; i < 6; ++i)
                acc[i] = __builtin_amdgcn_mfma_f32_16x16x32_f16(wr[i * 6 + c], bfv[c], acc[i], 0, 0, 0);
        #pragma unroll
        for (int c2 = 0; c2 < 2; ++c2)
            #pragma unroll
            for (int i = 0; i < 6; ++i) {
                const f16x8 wlt = *(const f16x8*)&Wl[(i * 2 + c2) * 512 + tid];
                acc[i] = __builtin_amdgcn_mfma_f32_16x16x32_f16(wlt, bfv[6 + c2], acc[i], 0, 0, 0);
            }
        #pragma unroll
        for (int i = 0; i < 6; ++i) {
            uint2 ph;
            ph.x = h2u(__floats2half2_rn(acc[i][0], acc[i][1]));
            ph.y = h2u(__floats2half2_rn(acc[i][2], acc[i][3]));
            *(uint2*)(Plh + col * 784 + (w * 96 + i * 16 + lq * 4)) = ph;
        }
        asm volatile("s_waitcnt lgkmcnt(0)" ::: "memory");
        __builtin_amdgcn_s_barrier();

        // ---- phase Y ----
        if (s_act[s]) {
            const __half* Pr = Plh + s * 784;
            const f16x8 R  = *(const f16x8*)(Pr + e0);
            const f16x8 Z  = *(const f16x8*)(Pr + 256 + e0);
            const f16x8 Nn = *(const f16x8*)(Pr + 512 + e0);
            const f32x4 br0 = *(const f32x4*)(Bl + e0),       br1 = *(const f32x4*)(Bl + e0 + 4);
            const f32x4 bz0 = *(const f32x4*)(Bl + 256 + e0), bz1 = *(const f32x4*)(Bl + 256 + e0 + 4);
            const f32x4 bn0 = *(const f32x4*)(Bl + 512 + e0), bn1 = *(const f32x4*)(Bl + 512 + e0 + 4);
            const uint4 hp4 = *(const uint4*)((const char*)Hl + s * 512 + ((g32 ^ (s & 7)) << 4));
            const __half2 q0 = u2h(hp4.x), q1 = u2h(hp4.y), q2 = u2h(hp4.z), q3 = u2h(hp4.w);
            const float hpv[8] = { __low2float(q0), __high2float(q0), __low2float(q1), __high2float(q1),
                                   __low2float(q2), __high2float(q2), __low2float(q3), __high2float(q3) };
            float hn[8];
            #pragma unroll
            for (int j = 0; j < 8; ++j) {
                const float ghr = (float)R[j]  + (j < 4 ? br0[j] : br1[j - 4]);
                const float ghz = (float)Z[j]  + (j < 4 ? bz0[j] : bz1[j - 4]);
                const float ghn = (float)Nn[j] + (j < 4 ? bn0[j] : bn1[j - 4]);
                const float rg = 1.f / (1.f + exp2f(-((float)gr[j] + ghr) * 1.44269504f));
                const float zg = 1.f / (1.f + exp2f(-((float)gz[j] + ghz) * 1.44269504f));
                const float nin = (float)gn[j] + rg * ghn;
                const float ex = exp2f(nin * 2.885390082f);
                const float ng = 1.f - 2.f / (ex + 1.f);
                hn[j] = (1.f - zg) * ng + zg * hpv[j];
            }
            uint4 hp;
            hp.x = h2u(__floats2half2_rn(hn[0], hn[1]));
            hp.y = h2u(__floats2half2_rn(hn[2], hn[3]));
            hp.z = h2u(__floats2half2_rn(hn[4], hn[5]));
            hp.w = h2u(__floats2half2_rn(hn[6], hn[7]));
            *(uint4*)(hs2 + (size_t)myrow * 128 + g32 * 4) = hp;
            if (myrow + 1 < s_end[s]) {
                *(uint4*)((char*)Hl + s * 512 + ((g32 ^ (s & 7)) << 4)) = hp;
                if (g32 == 0) s_row[s] = myrow + 1;
            } else if (nxte >= 0) {
                const int ln = nxte & 1023, st = (nxte >> 10) & 511, nb = nxte >> 19;
                *(uint4*)((char*)Hl + s * 512 + ((g32 ^ (s & 7)) << 4)) = su;
                if (g32 == 0) {
                    if (st == 0) { s_row[s] = nb * T_;          s_end[s] = nb * T_ + ln; }
                    else         { s_row[s] = nb * T_ + st + 1; s_end[s] = nb * T_ + st + ln; }
                    const int p = atomicAdd(&cur, 1);
                    s_nxt[s] = (p < hi) ? queue[p] : -1;
                }
            } else if (g32 == 0) {
                s_act[s] = 0;
            }
        }
        asm volatile("s_waitcnt lgkmcnt(0)" ::: "memory");
        __builtin_amdgcn_s_barrier();
    }
}

// ---------------------------------------------------------------------------
// Heads (unchanged, passed): one wave per output row, hs fp16.
// ---------------------------------------------------------------------------
__global__ __launch_bounds__(256)
void heads_kernel(const uint32_t* __restrict__ hs2, const float* __restrict__ Wa,
                  const float* __restrict__ ba, const float* __restrict__ Wc,
                  const float* __restrict__ bc, const int* __restrict__ action,
                  float* __restrict__ out)
{
    const int wid = threadIdx.x >> 6, lane = threadIdx.x & 63;
    const int row = blockIdx.x * 4 + wid;
    const uint2 hv2 = ((const uint2*)(hs2 + (size_t)row * 128))[lane];
    const __half2 ha = u2h(hv2.x), hb = u2h(hv2.y);
    const float h0f = __low2float(ha), h1f = __high2float(ha);
    const float h2f = __low2float(hb), h3f = __high2float(hb);
    float sums[11];
    #pragma unroll
    for (int n = 0; n < 11; ++n) {
        const float* wrow = (n < 10) ? (Wa + n * 256) : Wc;
        const float4 wv = ((const float4*)wrow)[lane];
        sums[n] = h0f * wv.x + h1f * wv.y + h2f * wv.z + h3f * wv.w;
    }
    #pragma unroll
    for (int n = 0; n < 11; ++n) {
        float v = sums[n];
        #pragma unroll
        for (int off = 32; off; off >>= 1) v += __shfl_xor(v, off);
        sums[n] = v;
    }
    float logits[10];
    #pragma unroll
    for (int n = 0; n < 10; ++n) logits[n] = sums[n] + ba[n];
    const float value = sums[10] + bc[0];
    float mx = logits[0];
    #pragma unroll
    for (int n = 1; n < 10; ++n) mx = fmaxf(mx, logits[n]);
    float ssum = 0.f, sdot = 0.f;
    #pragma unroll
    for (int n = 0; n < 10; ++n) {
        float d = logits[n] - mx;
        float e = exp2f(d * 1.44269504f);
        ssum += e; sdot += e * d;
    }
    const float lns = logf(ssum);
    const float lse = mx + lns;
    const float entropy = lns - sdot / ssum;
    const int a = action[row];
    float la = 0.f;
    #pragma unroll
    for (int n = 0; n < 10; ++n) la = (n == a) ? logits[n] : la;
    if (lane == 0) {
        out[row] = value;
        out[BT_ + row] = la - lse;
        out[2 * BT_ + row] = entropy;
    }
}

// ---------------------------------------------------------------------------
extern "C" void kernel_launch(void* const* d_in, const int* in_sizes, int n_in,
                              void* d_out, int out_size, void* d_ws, size_t ws_size,
                              hipStream_t stream)
{
    const float* obs    = (const float*)d_in[0];
    const int*   action = (const int*)d_in[1];
    const int*   masks  = (const int*)d_in[2];
    const float* h0     = (const float*)d_in[3];
    const float* W1     = (const float*)d_in[4];
    const float* b1     = (const float*)d_in[5];
    const float* Wih    = (const float*)d_in[6];
    const float* Whh    = (const float*)d_in[7];
    const float* bih    = (const float*)d_in[8];
    const float* bhh    = (const float*)d_in[9];
    const float* Wa     = (const float*)d_in[10];
    const float* ba     = (const float*)d_in[11];
    const float* Wc     = (const float*)d_in[12];
    const float* bc     = (const float*)d_in[13];
    float* out = (float*)d_out;

    char* p = (char*)d_ws;
    __half*   gx   = (__half*)p;    p += (size_t)BT_ * G_ * 2;      // 50.3 MB
    uint32_t* hs2  = (uint32_t*)p;  p += (size_t)BT_ * H_ * 2;      // 16.8 MB
    uint32_t* W1h  = (uint32_t*)p;  p += FEAT_ * OBS_ * 2;          // 131 KB
    uint32_t* Wihh = (uint32_t*)p;  p += G_ * FEAT_ * 2;            // 786 KB
    uint4*    WhhR = (uint4*)p;     p += 512 * 36 * 16;             // 295 KB
    uint4*    WhhL = (uint4*)p;     p += 12 * 512 * 16;             // 98 KB
    int*      queue= (int*)p;       p += B_ * 512 * 4;              // 131 KB
    int*      qctl = (int*)p;       p += 256;                       // [0]=tail

    // packs (pack_whh zeroes qctl) + segment queue build
    pack_half<<<(FEAT_ * OBS_ / 2 + 255) / 256, 256, 0, stream>>>(W1, W1h, FEAT_ * OBS_ / 2);
    pack_half<<<(G_ * FEAT_ / 2 + 255) / 256, 256, 0, stream>>>(Wih, Wihh, G_ * FEAT_ / 2);
    pack_whh<<<384, 256, 0, stream>>>(Whh, (uint32_t*)WhhR, (uint32_t*)WhhL, qctl);
    seg_build<<<B_, 512, 0, stream>>>(masks, queue, &qctl[0]);
    // gx = relu(obs@W1^T+b1) @ Wih^T + bih  -- fused, feat never leaves LDS
    fused_gemm<<<768, 512, 0, stream>>>(obs, (const __half*)W1h, (const __half*)Wihh, b1, bih, (uint32_t*)gx);
    // pre-pass: all h_prev==0 steps (elementwise, grid-stride)
    h0pre<<<2048, 256, 0, stream>>>(gx, bhh, masks, hs2);
    // MFMA slot-parallel recurrence (static slices, 2 barriers/iter, pre-pop)
    gru_mfma<<<256, 512, 0, stream>>>(gx, WhhR, WhhL, bhh, h0, queue, qctl, hs2);
    // heads
    heads_kernel<<<8192, 256, 0, stream>>>(hs2, Wa, ba, Wc, bc, action, out);
}